// Round 10
// baseline (772.746 us; speedup 1.0000x reference)
//
#include <hip/hip_runtime.h>
#include <hip/hip_bf16.h>
#include <cstdint>

#define NN 50000      // nodes
#define NE 500000     // edges
#define NR 4          // relations
#define NBATCH 512    // graphs
#define HD 256        // hidden/out width
#define NSEG (NN*NR)  // 200000 (dst,rel) segments
#define CHUNK 10000   // nodes per agg/gemm chunk

__constant__ int c_off[6] = {0,33,38,41,45,47};   // cumulative CARD offsets (total 50)

__device__ __forceinline__ float sigf(float x){ return 1.0f/(1.0f+__expf(-x)); }
__device__ __forceinline__ float bf2f(unsigned short b){ return __uint_as_float((unsigned)b<<16); }
__device__ __forceinline__ unsigned short f2bf(float f){
  unsigned u = __float_as_uint(f);
  return (unsigned short)((u + 0x7fffu + ((u>>16)&1u)) >> 16);   // RNE
}

typedef short bf16raw8 __attribute__((ext_vector_type(8)));
typedef float f32x4v  __attribute__((ext_vector_type(4)));
union LD16 { uint4 u; bf16raw8 v; };

// ---------- folded weight precompute (fp32):  out[rc][h] = emb_j[cl] . W[r, j*64.. , h] ----------
__global__ void k_weff(const float* __restrict__ e0,const float* __restrict__ e1,
                       const float* __restrict__ e2,const float* __restrict__ e3,
                       const float* __restrict__ e4,const float* __restrict__ e5,
                       const float* __restrict__ W, int rstride,
                       float* __restrict__ out){
  int rc = blockIdx.x, h = threadIdx.x;
  int r = rc/50, cg = rc%50;
  int j, cl;
  if      (cg>=47){j=5;cl=cg-47;} else if (cg>=45){j=4;cl=cg-45;}
  else if (cg>=41){j=3;cl=cg-41;} else if (cg>=38){j=2;cl=cg-38;}
  else if (cg>=33){j=1;cl=cg-33;} else            {j=0;cl=cg;}
  const float* emb = j==0?e0:j==1?e1:j==2?e2:j==3?e3:j==4?e4:e5;
  const float* wb = W + (size_t)r*rstride + (size_t)(j*64)*HD + h;
  float acc = 0.f;
  #pragma unroll 8
  for (int k=0;k<64;k++) acc += emb[cl*64+k]*wb[(size_t)k*HD];
  out[(size_t)rc*HD+h] = acc;
}

// ---------- segment counts only (cnt is 800KB, L2-resident) ----------
__global__ void k_cnt(const int* __restrict__ ei, const int* __restrict__ et,
                      int* __restrict__ cnt){
  int e = blockIdx.x*256 + threadIdx.x;
  if (e >= NE) return;
  atomicAdd(&cnt[ei[NE+e]*NR + et[e]], 1);
}

// ---------- B1t[o][k] bf16 from W1eff(200 rows)+R1eff(50 rows), zero-padded to 256 ----------
__global__ void k_b1t(const float* __restrict__ W1eff, const float* __restrict__ R1eff,
                      unsigned short* __restrict__ B1t){
  int id = blockIdx.x*256 + threadIdx.x;      // 256*256 total
  int k = id & 255, o = id >> 8;
  float v = 0.f;
  if (k < 200) v = W1eff[(size_t)k*HD + o];
  else if (k < 250) v = R1eff[(size_t)(k-200)*HD + o];
  B1t[(size_t)o*256 + k] = f2bf(v);
}

// ---------- transpose+convert fp32 W[K][O] -> bf16 Wt[o][dstOff+k] (row stride dstStride) ----------
__global__ void k_tconv(const float* __restrict__ W, unsigned short* __restrict__ Wt,
                        int K, int O, int dstStride, int dstOff){
  int id = blockIdx.x*256 + threadIdx.x;
  if (id >= K*O) return;
  int k = id % K, o = id / K;
  Wt[(size_t)o*dstStride + dstOff + k] = f2bf(W[(size_t)k*O + o]);
}

// ---------- 3-kernel exclusive prefix scan over cnt[NSEG] ----------
#define SC_T 256
#define SC_NB ((NSEG/4 + SC_T - 1)/SC_T)   // 196 blocks

__global__ void k_scan1(const int* __restrict__ cnt, int* __restrict__ bsum){
  __shared__ int sh[SC_T];
  int b = blockIdx.x, t = threadIdx.x;
  int i4 = b*SC_T + t;
  int s = 0;
  if (i4 < NSEG/4){ int4 v = ((const int4*)cnt)[i4]; s = v.x+v.y+v.z+v.w; }
  sh[t] = s; __syncthreads();
  for (int o=128;o>0;o>>=1){ if (t<o) sh[t]+=sh[t+o]; __syncthreads(); }
  if (t==0) bsum[b] = sh[0];
}

__global__ void k_scan2(const int* __restrict__ bsum, int* __restrict__ boff,
                        int* __restrict__ offs){
  __shared__ int sh[256];
  int t = threadIdx.x;
  int v = (t < SC_NB) ? bsum[t] : 0;
  sh[t] = v; __syncthreads();
  for (int o=1;o<256;o<<=1){
    int add = (t>=o) ? sh[t-o] : 0; __syncthreads();
    sh[t] += add; __syncthreads();
  }
  if (t < SC_NB) boff[t] = sh[t] - v;
  if (t == 255) offs[NSEG] = sh[255];
}

__global__ void k_scan3(const int* __restrict__ cnt, const int* __restrict__ boff,
                        int* __restrict__ offs, int* __restrict__ cursor){
  __shared__ int sh[SC_T];
  int b = blockIdx.x, t = threadIdx.x;
  int i4 = b*SC_T + t;
  int4 v = {0,0,0,0};
  if (i4 < NSEG/4) v = ((const int4*)cnt)[i4];
  int s = v.x+v.y+v.z+v.w;
  sh[t] = s; __syncthreads();
  for (int o=1;o<256;o<<=1){
    int add = (t>=o) ? sh[t-o] : 0; __syncthreads();
    sh[t] += add; __syncthreads();
  }
  if (i4 < NSEG/4){
    int excl = sh[t] - s + boff[b];
    int4 ov; ov.x = excl; ov.y = ov.x+v.x; ov.z = ov.y+v.y; ov.w = ov.z+v.z;
    ((int4*)offs)[i4] = ov; ((int4*)cursor)[i4] = ov;
  }
}

// ---------- bin edges into CSR slots by (dst,rel) ----------
__global__ void k_bin(const int* __restrict__ ei, const int* __restrict__ et,
                      int* __restrict__ cursor, int* __restrict__ esrc){
  int e = blockIdx.x*256 + threadIdx.x;
  if (e >= NE) return;
  int s = ei[e], d = ei[NE+e], t = et[e];
  int slot = atomicAdd(&cursor[d*NR + t], 1);
  esrc[slot] = s;
}

// ---------- A1[n][256] from CSR gather:
//            t<200: (r,bin) count/cnt ; t in [200,250): root one-hot ; else 0 ----------
__global__ void k_buildseg(const int* __restrict__ x, const int* __restrict__ offs,
                           const int* __restrict__ esrc, unsigned short* __restrict__ A1){
  int n = blockIdx.x, t = threadIdx.x;
  float v = 0.f;
  if (t < 200){
    int r = t/50, bin = t%50;
    int j, cl;
    if      (bin>=47){j=5;cl=bin-47;} else if (bin>=45){j=4;cl=bin-45;}
    else if (bin>=41){j=3;cl=bin-41;} else if (bin>=38){j=2;cl=bin-38;}
    else if (bin>=33){j=1;cl=bin-33;} else            {j=0;cl=bin;}
    int a = offs[n*NR+r], e2 = offs[n*NR+r+1];
    int c = 0;
    for (int e=a;e<e2;e++){
      int s = esrc[e];
      c += (x[s*6+j] == cl) ? 1 : 0;
    }
    v = (float)c / (float)max(e2-a, 1);
  } else if (t < 250){
    int cg = t - 200;
    #pragma unroll
    for (int j=0;j<6;j++) if (cg == c_off[j] + x[n*6+j]) v = 1.f;
  }
  A1[(size_t)n*256 + t] = f2bf(v);
}

// ---------- gather-aggregate (bf16 in/out, fp32 accum) ----------
__global__ void k_agg(const int* __restrict__ offs, const int* __restrict__ esrc,
                      const unsigned short* __restrict__ h1, unsigned short* __restrict__ agg,
                      int base, int m){
  int gid = blockIdx.x*256 + threadIdx.x;
  int n = gid >> 6;          // one wave per node
  if (n >= m) return;
  int lane = gid & 63;
  int gn = base + n;
  #pragma unroll
  for (int r=0;r<NR;r++){
    int a = offs[gn*NR+r], b = offs[gn*NR+r+1];
    float a0=0.f,a1=0.f,a2=0.f,a3=0.f;
    for (int e=a;e<b;e++){
      int s = esrc[e];
      ushort4 v = *(const ushort4*)(h1 + (size_t)s*HD + lane*4);
      a0+=bf2f(v.x); a1+=bf2f(v.y); a2+=bf2f(v.z); a3+=bf2f(v.w);
    }
    float iv = 1.0f / (float)max(b-a, 1);
    ushort4 o;
    o.x=f2bf(a0*iv); o.y=f2bf(a1*iv); o.z=f2bf(a2*iv); o.w=f2bf(a3*iv);
    *(ushort4*)(agg + (size_t)n*(NR*HD) + r*HD + lane*4) = o;
  }
}

// ---------- bf16 MFMA GEMM, no LDS, compile-time K, 2-deep register pipeline ----------
// C[M,256] = [A (NK1*32 cols) | A2 (NK2*32 cols)] @ Bt^T (+bias)(+sigmoid)
// block = 256 thr = 4 waves (2x2), block tile 128x128, wave tile 64x64 (4x4 frags 16x16x32)
template<int NK1, int NK2, bool SIG, bool F32OUT>
__global__ __launch_bounds__(256) void k_mfma(
    const unsigned short* __restrict__ A,  int lda,
    const unsigned short* __restrict__ A2, int lda2,
    const unsigned short* __restrict__ Bt,   // [256][K] bf16, row stride K
    const float* __restrict__ bias,          // [256] or null
    unsigned short* __restrict__ outB,       // [M][256] bf16 (if !F32OUT)
    float* __restrict__ outF,                // [M][256] f32  (if F32OUT)
    int M){
  constexpr int NK = NK1 + NK2;
  constexpr int K  = NK * 32;
  int tid = threadIdx.x;
  int wave = tid >> 6, lane = tid & 63;
  int wm = (wave >> 1) * 64, wn = (wave & 1) * 64;
  int bm = blockIdx.y * 128, bn = blockIdx.x * 128;
  int lrow = lane & 15, lk8 = (lane >> 4) * 8;

  // hoisted per-fragment base pointers (row clamp once)
  const unsigned short* aP[4];
  const unsigned short* a2P[4];
  const unsigned short* bP[4];
  #pragma unroll
  for (int mi=0;mi<4;mi++){
    int row = bm + wm + mi*16 + lrow; if (row > M-1) row = M-1;
    aP[mi]  = A  + (size_t)row*lda  + lk8;
    if (NK2 > 0) a2P[mi] = A2 + (size_t)row*lda2 + lk8;
  }
  #pragma unroll
  for (int nj=0;nj<4;nj++){
    int col = bn + wn + nj*16 + lrow;   // always < 256
    bP[nj] = Bt + (size_t)col*K + lk8;
  }

  f32x4v acc[4][4] = {};
  bf16raw8 aF[2][4], bF[2][4];

  // prefetch k-step 0
  #pragma unroll
  for (int mi=0;mi<4;mi++){ LD16 t; t.u = *(const uint4*)(aP[mi]); aF[0][mi]=t.v; }
  #pragma unroll
  for (int nj=0;nj<4;nj++){ LD16 t; t.u = *(const uint4*)(bP[nj]); bF[0][nj]=t.v; }

  #pragma unroll
  for (int k=0;k<NK;k++){
    constexpr int unused = 0; (void)unused;
    int cur = k & 1, nxt = cur ^ 1;
    if (k+1 < NK){
      if (k+1 < NK1){
        #pragma unroll
        for (int mi=0;mi<4;mi++){ LD16 t; t.u = *(const uint4*)(aP[mi] + (k+1)*32); aF[nxt][mi]=t.v; }
      } else {
        #pragma unroll
        for (int mi=0;mi<4;mi++){ LD16 t; t.u = *(const uint4*)(a2P[mi] + (k+1-NK1)*32); aF[nxt][mi]=t.v; }
      }
      #pragma unroll
      for (int nj=0;nj<4;nj++){ LD16 t; t.u = *(const uint4*)(bP[nj] + (k+1)*32); bF[nxt][nj]=t.v; }
    }
    #pragma unroll
    for (int mi=0;mi<4;mi++)
      #pragma unroll
      for (int nj=0;nj<4;nj++)
        acc[mi][nj] = __builtin_amdgcn_mfma_f32_16x16x32_bf16(aF[cur][mi], bF[cur][nj], acc[mi][nj], 0, 0, 0);
  }

  int r0 = (lane >> 4) * 4;
  #pragma unroll
  for (int mi = 0; mi < 4; mi++){
    #pragma unroll
    for (int i = 0; i < 4; i++){
      int row = bm + wm + mi*16 + r0 + i;
      if (row >= M) continue;
      #pragma unroll
      for (int nj = 0; nj < 4; nj++){
        int col = bn + wn + nj*16 + lrow;
        float v = acc[mi][nj][i];
        if (bias) v += bias[col];
        if (SIG) v = sigf(v);
        if (F32OUT) outF[(size_t)row*HD + col] = v;
        else        outB[(size_t)row*HD + col] = f2bf(v);
      }
    }
  }
}

// ---------- BN stats (training-mode, biased var) ----------
__global__ void k_bnstats(const float* __restrict__ g, float* __restrict__ chan){
  int c = threadIdx.x;
  int r0 = blockIdx.x*128;
  int rend = min(r0+128, NN);
  float s=0.f, q=0.f;
  for (int row=r0; row<rend; row++){
    float v = g[(size_t)row*HD + c];
    s += v; q += v*v;
  }
  atomicAdd(&chan[c], s); atomicAdd(&chan[HD+c], q);
}

__global__ void k_bnfin(const float* __restrict__ chan, const float* __restrict__ bng,
                        const float* __restrict__ bnb, float* __restrict__ bnp){
  int c = threadIdx.x;
  float mu = chan[c]/(float)NN;
  float var = chan[HD+c]/(float)NN - mu*mu;
  float scale = bng[c]*rsqrtf(var + 1e-5f);
  bnp[c] = bnb[c] - mu*scale;     // shift
  bnp[HD+c] = scale;              // scale
}

// ---------- gate[n] = relu(BN(g[n])) . g2_w + g2_b (no atomics) ----------
__global__ void k_gate(const float* __restrict__ g, const float* __restrict__ bnp,
                       const float* __restrict__ g2w, const float* __restrict__ g2b,
                       float* __restrict__ gate){
  int lane = threadIdx.x & 63;
  int n = blockIdx.x*4 + (threadIdx.x>>6);
  if (n >= NN) return;
  float s = 0.f;
  #pragma unroll
  for (int k=0;k<4;k++){
    int c = lane + k*64;
    float v = g[(size_t)n*HD + c]*bnp[HD+c] + bnp[c];
    v = fmaxf(v, 0.f);
    s += v * g2w[c];
  }
  #pragma unroll
  for (int o=32;o>0;o>>=1) s += __shfl_down(s, o);
  if (lane==0) gate[n] = s + g2b[0];
}

// ---------- per-graph offsets from SORTED batch ----------
__global__ void k_goffs(const int* __restrict__ batch, int* __restrict__ goffs){
  int n = blockIdx.x*256 + threadIdx.x;
  if (n >= NN) return;
  int b = batch[n];
  int prev = (n == 0) ? -1 : batch[n-1];
  for (int gg = prev+1; gg <= b; gg++) goffs[gg] = n;
  if (n == NN-1){ for (int gg = b+1; gg <= NBATCH; gg++) goffs[gg] = NN; }
}

// ---------- fused per-graph: softmax(gate) -> weighted pool of h2 -> out = sigmoid(.glw+glb) ----------
__global__ __launch_bounds__(256) void k_poolg(
    const unsigned short* __restrict__ h2, const float* __restrict__ gate,
    const int* __restrict__ goffs, const float* __restrict__ glw,
    const float* __restrict__ glb, float* __restrict__ out){
  __shared__ float red[256];
  int b = blockIdx.x, tid = threadIdx.x;
  int a = goffs[b], e = goffs[b+1];

  // phase 1: max over gate[a:e]
  float m = -3.4e38f;
  for (int n = a + tid; n < e; n += 256) m = fmaxf(m, gate[n]);
  red[tid] = m; __syncthreads();
  for (int o = 128; o > 0; o >>= 1){ if (tid < o) red[tid] = fmaxf(red[tid], red[tid+o]); __syncthreads(); }
  m = red[0]; __syncthreads();

  // phase 2: sum of exp
  float s = 0.f;
  for (int n = a + tid; n < e; n += 256) s += __expf(gate[n] - m);
  red[tid] = s; __syncthreads();
  for (int o = 128; o > 0; o >>= 1){ if (tid < o) red[tid] += red[tid+o]; __syncthreads(); }
  float denom = red[0] + 1e-16f; __syncthreads();

  // phase 3: per-channel weighted accumulate (tid = channel)
  float acc = 0.f;
  #pragma unroll 4
  for (int n = a; n < e; n++){
    float ev = __expf(gate[n] - m);
    acc += ev * bf2f(h2[(size_t)n*HD + tid]);
  }
  acc /= denom;

  // phase 4: dot with glw -> out
  red[tid] = acc * glw[tid]; __syncthreads();
  for (int o = 128; o > 0; o >>= 1){ if (tid < o) red[tid] += red[tid+o]; __syncthreads(); }
  if (tid == 0) out[b] = sigf(red[0] + glb[0]);
}

extern "C" void kernel_launch(void* const* d_in, const int* in_sizes, int n_in,
                              void* d_out, int out_size, void* d_ws, size_t ws_size,
                              hipStream_t stream) {
  const int* x     = (const int*)d_in[0];
  const int* ei    = (const int*)d_in[1];
  const int* et    = (const int*)d_in[2];
  const int* batch = (const int*)d_in[3];
  const float* emb0 = (const float*)d_in[4];
  const float* emb1 = (const float*)d_in[5];
  const float* emb2 = (const float*)d_in[6];
  const float* emb3 = (const float*)d_in[7];
  const float* emb4 = (const float*)d_in[8];
  const float* emb5 = (const float*)d_in[9];
  const float* W1    = (const float*)d_in[10];
  const float* root1 = (const float*)d_in[11];
  const float* b1    = (const float*)d_in[12];
  const float* W2    = (const float*)d_in[13];  // [R,H,O] flat == [1024,256]
  const float* root2 = (const float*)d_in[14];
  const float* b2    = (const float*)d_in[15];
  const float* g1w   = (const float*)d_in[16];
  const float* g1b   = (const float*)d_in[17];
  const float* bng   = (const float*)d_in[18];
  const float* bnb   = (const float*)d_in[19];
  const float* g2w   = (const float*)d_in[20];
  const float* g2b   = (const float*)d_in[21];
  const float* glw   = (const float*)d_in[22];
  const float* glb   = (const float*)d_in[23];
  float* out = (float*)d_out;

  // ---- workspace carve-up (256B aligned), total ≈ 128 MB ----
  char* w = (char*)d_ws;
  auto alloc = [&](size_t bytes)->char* {
    char* p = w; w += (bytes + 255) & ~(size_t)255; return p;
  };
  char* gReg = alloc((size_t)NN*HD*sizeof(float));      // A1 (bf16), later g (f32)
  unsigned short* A1 = (unsigned short*)gReg;
  float* g = (float*)gReg;
  unsigned short* agg  = (unsigned short*)alloc((size_t)CHUNK*NR*HD*2);  // 20.5 MB
  unsigned short* h1   = (unsigned short*)alloc((size_t)NN*HD*2);        // 25.6 MB
  unsigned short* hRes = (unsigned short*)alloc((size_t)NN*HD*2);        // 25.6 MB
  int*   cnt  = (int*)alloc((size_t)NSEG*sizeof(int));
  int*   offs = (int*)alloc((size_t)(NSEG+1)*sizeof(int));
  int*   cursor=(int*)alloc((size_t)NSEG*sizeof(int));
  int*   bsum = (int*)alloc((size_t)SC_NB*sizeof(int));
  int*   boff = (int*)alloc((size_t)SC_NB*sizeof(int));
  int*   esrc = (int*)alloc((size_t)NE*sizeof(int));
  float* W1eff= (float*)alloc((size_t)200*HD*sizeof(float));
  float* R1eff= (float*)alloc((size_t)50*HD*sizeof(float));
  unsigned short* B1t  = (unsigned short*)alloc((size_t)256*256*2);
  unsigned short* BtL2 = (unsigned short*)alloc((size_t)256*1280*2);   // [root2 | W2] transposed
  unsigned short* g1wt = (unsigned short*)alloc((size_t)256*256*2);
  float* gate = (float*)alloc((size_t)NN*sizeof(float));
  int*   goffs= (int*)alloc((size_t)(NBATCH+1)*sizeof(int));
  float* chan = (float*)alloc((size_t)2*HD*sizeof(float));
  float* bnp  = (float*)alloc((size_t)2*HD*sizeof(float));

  // ---- zero init ----
  hipMemsetAsync(cnt,  0, (size_t)NSEG*sizeof(int), stream);
  hipMemsetAsync(chan, 0, (size_t)2*HD*sizeof(float), stream);

  // ---- folded layer-1 weights (fp32), then bf16 transposed weight assembly ----
  k_weff<<<NR*50, HD, 0, stream>>>(emb0,emb1,emb2,emb3,emb4,emb5, W1, 384*HD, W1eff);
  k_weff<<<50,    HD, 0, stream>>>(emb0,emb1,emb2,emb3,emb4,emb5, root1, 0, R1eff);
  k_b1t<<<256, 256, 0, stream>>>(W1eff, R1eff, B1t);
  k_tconv<<<256, 256, 0, stream>>>(root2, BtL2, 256, 256, 1280, 0);
  k_tconv<<<1024, 256, 0, stream>>>(W2, BtL2, 1024, 256, 1280, 256);
  k_tconv<<<256, 256, 0, stream>>>(g1w, g1wt, 256, 256, 256, 0);

  // ---- CSR build (counts -> scan -> bin) ----
  k_cnt<<<(NE+255)/256, 256, 0, stream>>>(ei, et, cnt);
  k_scan1<<<SC_NB, SC_T, 0, stream>>>(cnt, bsum);
  k_scan2<<<1, 256, 0, stream>>>(bsum, boff, offs);
  k_scan3<<<SC_NB, SC_T, 0, stream>>>(cnt, boff, offs, cursor);
  k_bin<<<(NE+255)/256, 256, 0, stream>>>(ei, et, cursor, esrc);

  // ---- A1 from CSR gather ----
  k_buildseg<<<NN, 256, 0, stream>>>(x, offs, esrc, A1);

  // ---- per-graph offsets (independent) ----
  k_goffs<<<(NN+255)/256, 256, 0, stream>>>(batch, goffs);

  // ---- layer 1 GEMM: h1 = sigmoid(A1 @ B1 + b1) ----
  dim3 gFull(2, (NN+127)/128);
  k_mfma<8,0,true,false><<<gFull, 256, 0, stream>>>(A1, 256, nullptr, 0, B1t, b1, h1, nullptr, NN);

  // ---- layer 2: chunked agg + dual-A K=1280 GEMM ([h1 | agg] @ [root2;W2]) + sigmoid ----
  for (int c0 = 0; c0 < NN; c0 += CHUNK){
    int m = min(CHUNK, NN - c0);
    k_agg<<<(m*64+255)/256, 256, 0, stream>>>(offs, esrc, h1, agg, c0, m);
    dim3 gC(2, (m+127)/128);
    k_mfma<8,32,true,false><<<gC, 256, 0, stream>>>(h1 + (size_t)c0*HD, 256, agg, NR*HD,
                                                    BtL2, b2, hRes + (size_t)c0*HD, nullptr, m);
  }
  // hRes = h2 (bf16)

  // ---- gate linear: g = h2 @ g1w + g1b (fp32 out), BN stats ----
  k_mfma<8,0,false,true><<<gFull, 256, 0, stream>>>(hRes, 256, nullptr, 0, g1wt, g1b, nullptr, g, NN);
  k_bnstats<<<(NN+127)/128, HD, 0, stream>>>(g, chan);
  k_bnfin<<<1, HD, 0, stream>>>(chan, bng, bnb, bnp);

  // ---- gate scalar (no atomics) + fused per-graph softmax/pool/output ----
  k_gate<<<(NN+3)/4, 256, 0, stream>>>(g, bnp, g2w, g2b, gate);
  k_poolg<<<NBATCH, 256, 0, stream>>>(hRes, gate, goffs, glw, glb, out);
}

// Round 11
// 704.481 us; speedup vs baseline: 1.0969x; 1.0969x over previous
//
#include <hip/hip_runtime.h>
#include <hip/hip_bf16.h>
#include <cstdint>

#define NN 50000      // nodes
#define NE 500000     // edges
#define NR 4          // relations
#define NBATCH 512    // graphs
#define HD 256        // hidden/out width
#define NSEG (NN*NR)  // 200000 (dst,rel) segments
#define CHUNK 25000   // nodes per agg/gemm chunk (agg buf = 51.2 MB)

__constant__ int c_off[6] = {0,33,38,41,45,47};   // cumulative CARD offsets (total 50)

__device__ __forceinline__ float sigf(float x){ return 1.0f/(1.0f+__expf(-x)); }
__device__ __forceinline__ float bf2f(unsigned short b){ return __uint_as_float((unsigned)b<<16); }
__device__ __forceinline__ unsigned short f2bf(float f){
  unsigned u = __float_as_uint(f);
  return (unsigned short)((u + 0x7fffu + ((u>>16)&1u)) >> 16);   // RNE
}

typedef short bf16raw8 __attribute__((ext_vector_type(8)));
typedef float f32x4v  __attribute__((ext_vector_type(4)));
union LD16 { uint4 u; bf16raw8 v; };

// ---------- folded weight precompute (fp32):  out[rc][h] = emb_j[cl] . W[r, j*64.. , h] ----------
__global__ void k_weff(const float* __restrict__ e0,const float* __restrict__ e1,
                       const float* __restrict__ e2,const float* __restrict__ e3,
                       const float* __restrict__ e4,const float* __restrict__ e5,
                       const float* __restrict__ W, int rstride,
                       float* __restrict__ out){
  int rc = blockIdx.x, h = threadIdx.x;
  int r = rc/50, cg = rc%50;
  int j, cl;
  if      (cg>=47){j=5;cl=cg-47;} else if (cg>=45){j=4;cl=cg-45;}
  else if (cg>=41){j=3;cl=cg-41;} else if (cg>=38){j=2;cl=cg-38;}
  else if (cg>=33){j=1;cl=cg-33;} else            {j=0;cl=cg;}
  const float* emb = j==0?e0:j==1?e1:j==2?e2:j==3?e3:j==4?e4:e5;
  const float* wb = W + (size_t)r*rstride + (size_t)(j*64)*HD + h;
  float acc = 0.f;
  #pragma unroll 8
  for (int k=0;k<64;k++) acc += emb[cl*64+k]*wb[(size_t)k*HD];
  out[(size_t)rc*HD+h] = acc;
}

// ---------- segment counts only (cnt is 800KB, L2-resident) ----------
__global__ void k_cnt(const int* __restrict__ ei, const int* __restrict__ et,
                      int* __restrict__ cnt){
  int e = blockIdx.x*256 + threadIdx.x;
  if (e >= NE) return;
  atomicAdd(&cnt[ei[NE+e]*NR + et[e]], 1);
}

// ---------- B1t[o][k] bf16 from W1eff(200 rows)+R1eff(50 rows), zero-padded to 256 ----------
__global__ void k_b1t(const float* __restrict__ W1eff, const float* __restrict__ R1eff,
                      unsigned short* __restrict__ B1t){
  int id = blockIdx.x*256 + threadIdx.x;      // 256*256 total
  int k = id & 255, o = id >> 8;
  float v = 0.f;
  if (k < 200) v = W1eff[(size_t)k*HD + o];
  else if (k < 250) v = R1eff[(size_t)(k-200)*HD + o];
  B1t[(size_t)o*256 + k] = f2bf(v);
}

// ---------- transpose+convert fp32 W[K][O] -> bf16 Wt[o][dstOff+k] (row stride dstStride) ----------
__global__ void k_tconv(const float* __restrict__ W, unsigned short* __restrict__ Wt,
                        int K, int O, int dstStride, int dstOff){
  int id = blockIdx.x*256 + threadIdx.x;
  if (id >= K*O) return;
  int k = id % K, o = id / K;
  Wt[(size_t)o*dstStride + dstOff + k] = f2bf(W[(size_t)k*O + o]);
}

// ---------- 3-kernel exclusive prefix scan over cnt[NSEG] ----------
#define SC_T 256
#define SC_NB ((NSEG/4 + SC_T - 1)/SC_T)   // 196 blocks

__global__ void k_scan1(const int* __restrict__ cnt, int* __restrict__ bsum){
  __shared__ int sh[SC_T];
  int b = blockIdx.x, t = threadIdx.x;
  int i4 = b*SC_T + t;
  int s = 0;
  if (i4 < NSEG/4){ int4 v = ((const int4*)cnt)[i4]; s = v.x+v.y+v.z+v.w; }
  sh[t] = s; __syncthreads();
  for (int o=128;o>0;o>>=1){ if (t<o) sh[t]+=sh[t+o]; __syncthreads(); }
  if (t==0) bsum[b] = sh[0];
}

__global__ void k_scan2(const int* __restrict__ bsum, int* __restrict__ boff,
                        int* __restrict__ offs){
  __shared__ int sh[256];
  int t = threadIdx.x;
  int v = (t < SC_NB) ? bsum[t] : 0;
  sh[t] = v; __syncthreads();
  for (int o=1;o<256;o<<=1){
    int add = (t>=o) ? sh[t-o] : 0; __syncthreads();
    sh[t] += add; __syncthreads();
  }
  if (t < SC_NB) boff[t] = sh[t] - v;
  if (t == 255) offs[NSEG] = sh[255];
}

__global__ void k_scan3(const int* __restrict__ cnt, const int* __restrict__ boff,
                        int* __restrict__ offs, int* __restrict__ cursor){
  __shared__ int sh[SC_T];
  int b = blockIdx.x, t = threadIdx.x;
  int i4 = b*SC_T + t;
  int4 v = {0,0,0,0};
  if (i4 < NSEG/4) v = ((const int4*)cnt)[i4];
  int s = v.x+v.y+v.z+v.w;
  sh[t] = s; __syncthreads();
  for (int o=1;o<256;o<<=1){
    int add = (t>=o) ? sh[t-o] : 0; __syncthreads();
    sh[t] += add; __syncthreads();
  }
  if (i4 < NSEG/4){
    int excl = sh[t] - s + boff[b];
    int4 ov; ov.x = excl; ov.y = ov.x+v.x; ov.z = ov.y+v.y; ov.w = ov.z+v.z;
    ((int4*)offs)[i4] = ov; ((int4*)cursor)[i4] = ov;
  }
}

// ---------- bin edges into CSR slots by (dst,rel) ----------
__global__ void k_bin(const int* __restrict__ ei, const int* __restrict__ et,
                      int* __restrict__ cursor, int* __restrict__ esrc){
  int e = blockIdx.x*256 + threadIdx.x;
  if (e >= NE) return;
  int s = ei[e], d = ei[NE+e], t = et[e];
  int slot = atomicAdd(&cursor[d*NR + t], 1);
  esrc[slot] = s;
}

// ---------- A1[n][256] from CSR gather:
//            t<200: (r,bin) count/cnt ; t in [200,250): root one-hot ; else 0 ----------
__global__ void k_buildseg(const int* __restrict__ x, const int* __restrict__ offs,
                           const int* __restrict__ esrc, unsigned short* __restrict__ A1){
  int n = blockIdx.x, t = threadIdx.x;
  float v = 0.f;
  if (t < 200){
    int r = t/50, bin = t%50;
    int j, cl;
    if      (bin>=47){j=5;cl=bin-47;} else if (bin>=45){j=4;cl=bin-45;}
    else if (bin>=41){j=3;cl=bin-41;} else if (bin>=38){j=2;cl=bin-38;}
    else if (bin>=33){j=1;cl=bin-33;} else            {j=0;cl=bin;}
    int a = offs[n*NR+r], e2 = offs[n*NR+r+1];
    int c = 0;
    for (int e=a;e<e2;e++){
      int s = esrc[e];
      c += (x[s*6+j] == cl) ? 1 : 0;
    }
    v = (float)c / (float)max(e2-a, 1);
  } else if (t < 250){
    int cg = t - 200;
    #pragma unroll
    for (int j=0;j<6;j++) if (cg == c_off[j] + x[n*6+j]) v = 1.f;
  }
  A1[(size_t)n*256 + t] = f2bf(v);
}

// ---------- gather-aggregate (bf16 in/out, fp32 accum) ----------
__global__ void k_agg(const int* __restrict__ offs, const int* __restrict__ esrc,
                      const unsigned short* __restrict__ h1, unsigned short* __restrict__ agg,
                      int base, int m){
  int gid = blockIdx.x*256 + threadIdx.x;
  int n = gid >> 6;          // one wave per node
  if (n >= m) return;
  int lane = gid & 63;
  int gn = base + n;
  #pragma unroll
  for (int r=0;r<NR;r++){
    int a = offs[gn*NR+r], b = offs[gn*NR+r+1];
    float a0=0.f,a1=0.f,a2=0.f,a3=0.f;
    for (int e=a;e<b;e++){
      int s = esrc[e];
      ushort4 v = *(const ushort4*)(h1 + (size_t)s*HD + lane*4);
      a0+=bf2f(v.x); a1+=bf2f(v.y); a2+=bf2f(v.z); a3+=bf2f(v.w);
    }
    float iv = 1.0f / (float)max(b-a, 1);
    ushort4 o;
    o.x=f2bf(a0*iv); o.y=f2bf(a1*iv); o.z=f2bf(a2*iv); o.w=f2bf(a3*iv);
    *(ushort4*)(agg + (size_t)n*(NR*HD) + r*HD + lane*4) = o;
  }
}

// ---------- bf16 MFMA GEMM, no LDS, compile-time K, 8-wave TLP + 2-deep pipeline ----------
// C[M,256] = [A (NK1*32 cols) | A2 (NK2*32 cols)] @ Bt^T (+bias)(+sigmoid), bf16 out
// block = 512 thr = 8 waves (4x2), block tile 128x128, wave tile 32x64 (2x4 frags 16x16x32)
template<int NK1, int NK2, bool SIG>
__global__ __launch_bounds__(512) void k_mfma(
    const unsigned short* __restrict__ A,  int lda,
    const unsigned short* __restrict__ A2, int lda2,
    const unsigned short* __restrict__ Bt,   // [256][K] bf16, row stride K
    const float* __restrict__ bias,          // [256] or null
    unsigned short* __restrict__ outB,       // [M][256] bf16
    int M){
  constexpr int NK = NK1 + NK2;
  constexpr int K  = NK * 32;
  int tid = threadIdx.x;
  int wave = tid >> 6, lane = tid & 63;
  int wm = (wave >> 1) * 32, wn = (wave & 1) * 64;
  int bm = blockIdx.y * 128, bn = blockIdx.x * 128;
  int lrow = lane & 15, lk8 = (lane >> 4) * 8;

  // hoisted per-fragment base pointers (row clamp once)
  const unsigned short* aP[2];
  const unsigned short* a2P[2];
  const unsigned short* bP[4];
  #pragma unroll
  for (int mi=0;mi<2;mi++){
    int row = bm + wm + mi*16 + lrow; if (row > M-1) row = M-1;
    aP[mi]  = A  + (size_t)row*lda  + lk8;
    if (NK2 > 0) a2P[mi] = A2 + (size_t)row*lda2 + lk8;
  }
  #pragma unroll
  for (int nj=0;nj<4;nj++){
    int col = bn + wn + nj*16 + lrow;   // always < 256
    bP[nj] = Bt + (size_t)col*K + lk8;
  }

  f32x4v acc[2][4] = {};
  bf16raw8 aF[2][2], bF[2][4];

  // prefetch k-step 0
  #pragma unroll
  for (int mi=0;mi<2;mi++){ LD16 t; t.u = *(const uint4*)(aP[mi]); aF[0][mi]=t.v; }
  #pragma unroll
  for (int nj=0;nj<4;nj++){ LD16 t; t.u = *(const uint4*)(bP[nj]); bF[0][nj]=t.v; }

  #pragma unroll
  for (int k=0;k<NK;k++){
    int cur = k & 1, nxt = cur ^ 1;
    if (k+1 < NK){
      if (k+1 < NK1){
        #pragma unroll
        for (int mi=0;mi<2;mi++){ LD16 t; t.u = *(const uint4*)(aP[mi] + (k+1)*32); aF[nxt][mi]=t.v; }
      } else {
        #pragma unroll
        for (int mi=0;mi<2;mi++){ LD16 t; t.u = *(const uint4*)(a2P[mi] + (k+1-NK1)*32); aF[nxt][mi]=t.v; }
      }
      #pragma unroll
      for (int nj=0;nj<4;nj++){ LD16 t; t.u = *(const uint4*)(bP[nj] + (k+1)*32); bF[nxt][nj]=t.v; }
    }
    #pragma unroll
    for (int mi=0;mi<2;mi++)
      #pragma unroll
      for (int nj=0;nj<4;nj++)
        acc[mi][nj] = __builtin_amdgcn_mfma_f32_16x16x32_bf16(aF[cur][mi], bF[cur][nj], acc[mi][nj], 0, 0, 0);
  }

  int r0 = (lane >> 4) * 4;
  #pragma unroll
  for (int mi = 0; mi < 2; mi++){
    #pragma unroll
    for (int i = 0; i < 4; i++){
      int row = bm + wm + mi*16 + r0 + i;
      if (row >= M) continue;
      #pragma unroll
      for (int nj = 0; nj < 4; nj++){
        int col = bn + wn + nj*16 + lrow;
        float v = acc[mi][nj][i];
        if (bias) v += bias[col];
        if (SIG) v = sigf(v);
        outB[(size_t)row*HD + col] = f2bf(v);
      }
    }
  }
}

// ---------- BN stats over bf16 g (training-mode, biased var) ----------
__global__ void k_bnstats(const unsigned short* __restrict__ g, float* __restrict__ chan){
  int c = threadIdx.x;
  int r0 = blockIdx.x*128;
  int rend = min(r0+128, NN);
  float s=0.f, q=0.f;
  for (int row=r0; row<rend; row++){
    float v = bf2f(g[(size_t)row*HD + c]);
    s += v; q += v*v;
  }
  atomicAdd(&chan[c], s); atomicAdd(&chan[HD+c], q);
}

__global__ void k_bnfin(const float* __restrict__ chan, const float* __restrict__ bng,
                        const float* __restrict__ bnb, float* __restrict__ bnp){
  int c = threadIdx.x;
  float mu = chan[c]/(float)NN;
  float var = chan[HD+c]/(float)NN - mu*mu;
  float scale = bng[c]*rsqrtf(var + 1e-5f);
  bnp[c] = bnb[c] - mu*scale;     // shift
  bnp[HD+c] = scale;              // scale
}

// ---------- gate[n] = relu(BN(g[n])) . g2_w + g2_b (no atomics, bf16 g) ----------
__global__ void k_gate(const unsigned short* __restrict__ g, const float* __restrict__ bnp,
                       const float* __restrict__ g2w, const float* __restrict__ g2b,
                       float* __restrict__ gate){
  int lane = threadIdx.x & 63;
  int n = blockIdx.x*4 + (threadIdx.x>>6);
  if (n >= NN) return;
  float s = 0.f;
  #pragma unroll
  for (int k=0;k<4;k++){
    int c = lane + k*64;
    float v = bf2f(g[(size_t)n*HD + c])*bnp[HD+c] + bnp[c];
    v = fmaxf(v, 0.f);
    s += v * g2w[c];
  }
  #pragma unroll
  for (int o=32;o>0;o>>=1) s += __shfl_down(s, o);
  if (lane==0) gate[n] = s + g2b[0];
}

// ---------- per-graph offsets from SORTED batch ----------
__global__ void k_goffs(const int* __restrict__ batch, int* __restrict__ goffs){
  int n = blockIdx.x*256 + threadIdx.x;
  if (n >= NN) return;
  int b = batch[n];
  int prev = (n == 0) ? -1 : batch[n-1];
  for (int gg = prev+1; gg <= b; gg++) goffs[gg] = n;
  if (n == NN-1){ for (int gg = b+1; gg <= NBATCH; gg++) goffs[gg] = NN; }
}

// ---------- fused per-graph: softmax(gate) -> weighted pool of h2 -> out = sigmoid(.glw+glb) ----------
__global__ __launch_bounds__(256) void k_poolg(
    const unsigned short* __restrict__ h2, const float* __restrict__ gate,
    const int* __restrict__ goffs, const float* __restrict__ glw,
    const float* __restrict__ glb, float* __restrict__ out){
  __shared__ float red[256];
  int b = blockIdx.x, tid = threadIdx.x;
  int a = goffs[b], e = goffs[b+1];

  // phase 1: max over gate[a:e]
  float m = -3.4e38f;
  for (int n = a + tid; n < e; n += 256) m = fmaxf(m, gate[n]);
  red[tid] = m; __syncthreads();
  for (int o = 128; o > 0; o >>= 1){ if (tid < o) red[tid] = fmaxf(red[tid], red[tid+o]); __syncthreads(); }
  m = red[0]; __syncthreads();

  // phase 2: sum of exp
  float s = 0.f;
  for (int n = a + tid; n < e; n += 256) s += __expf(gate[n] - m);
  red[tid] = s; __syncthreads();
  for (int o = 128; o > 0; o >>= 1){ if (tid < o) red[tid] += red[tid+o]; __syncthreads(); }
  float denom = red[0] + 1e-16f; __syncthreads();

  // phase 3: per-channel weighted accumulate (tid = channel)
  float acc = 0.f;
  #pragma unroll 4
  for (int n = a; n < e; n++){
    float ev = __expf(gate[n] - m);
    acc += ev * bf2f(h2[(size_t)n*HD + tid]);
  }
  acc /= denom;

  // phase 4: dot with glw -> out
  red[tid] = acc * glw[tid]; __syncthreads();
  for (int o = 128; o > 0; o >>= 1){ if (tid < o) red[tid] += red[tid+o]; __syncthreads(); }
  if (tid == 0) out[b] = sigf(red[0] + glb[0]);
}

extern "C" void kernel_launch(void* const* d_in, const int* in_sizes, int n_in,
                              void* d_out, int out_size, void* d_ws, size_t ws_size,
                              hipStream_t stream) {
  const int* x     = (const int*)d_in[0];
  const int* ei    = (const int*)d_in[1];
  const int* et    = (const int*)d_in[2];
  const int* batch = (const int*)d_in[3];
  const float* emb0 = (const float*)d_in[4];
  const float* emb1 = (const float*)d_in[5];
  const float* emb2 = (const float*)d_in[6];
  const float* emb3 = (const float*)d_in[7];
  const float* emb4 = (const float*)d_in[8];
  const float* emb5 = (const float*)d_in[9];
  const float* W1    = (const float*)d_in[10];
  const float* root1 = (const float*)d_in[11];
  const float* b1    = (const float*)d_in[12];
  const float* W2    = (const float*)d_in[13];  // [R,H,O] flat == [1024,256]
  const float* root2 = (const float*)d_in[14];
  const float* b2    = (const float*)d_in[15];
  const float* g1w   = (const float*)d_in[16];
  const float* g1b   = (const float*)d_in[17];
  const float* bng   = (const float*)d_in[18];
  const float* bnb   = (const float*)d_in[19];
  const float* g2w   = (const float*)d_in[20];
  const float* g2b   = (const float*)d_in[21];
  const float* glw   = (const float*)d_in[22];
  const float* glb   = (const float*)d_in[23];
  float* out = (float*)d_out;

  // ---- workspace carve-up (256B aligned), total ≈ 154 MB ----
  char* w = (char*)d_ws;
  auto alloc = [&](size_t bytes)->char* {
    char* p = w; w += (bytes + 255) & ~(size_t)255; return p;
  };
  char* gReg = alloc((size_t)NN*HD*2);                  // A1 (bf16), later g (bf16)
  unsigned short* A1 = (unsigned short*)gReg;
  unsigned short* g  = (unsigned short*)gReg;
  unsigned short* agg  = (unsigned short*)alloc((size_t)CHUNK*NR*HD*2);  // 51.2 MB
  unsigned short* h1   = (unsigned short*)alloc((size_t)NN*HD*2);        // 25.6 MB
  unsigned short* hRes = (unsigned short*)alloc((size_t)NN*HD*2);        // 25.6 MB
  int*   cnt  = (int*)alloc((size_t)NSEG*sizeof(int));
  int*   offs = (int*)alloc((size_t)(NSEG+1)*sizeof(int));
  int*   cursor=(int*)alloc((size_t)NSEG*sizeof(int));
  int*   bsum = (int*)alloc((size_t)SC_NB*sizeof(int));
  int*   boff = (int*)alloc((size_t)SC_NB*sizeof(int));
  int*   esrc = (int*)alloc((size_t)NE*sizeof(int));
  float* W1eff= (float*)alloc((size_t)200*HD*sizeof(float));
  float* R1eff= (float*)alloc((size_t)50*HD*sizeof(float));
  unsigned short* B1t  = (unsigned short*)alloc((size_t)256*256*2);
  unsigned short* BtL2 = (unsigned short*)alloc((size_t)256*1280*2);   // [root2 | W2] transposed
  unsigned short* g1wt = (unsigned short*)alloc((size_t)256*256*2);
  float* gate = (float*)alloc((size_t)NN*sizeof(float));
  int*   goffs= (int*)alloc((size_t)(NBATCH+1)*sizeof(int));
  float* chan = (float*)alloc((size_t)2*HD*sizeof(float));
  float* bnp  = (float*)alloc((size_t)2*HD*sizeof(float));

  // ---- zero init ----
  hipMemsetAsync(cnt,  0, (size_t)NSEG*sizeof(int), stream);
  hipMemsetAsync(chan, 0, (size_t)2*HD*sizeof(float), stream);

  // ---- folded layer-1 weights (fp32), then bf16 transposed weight assembly ----
  k_weff<<<NR*50, HD, 0, stream>>>(emb0,emb1,emb2,emb3,emb4,emb5, W1, 384*HD, W1eff);
  k_weff<<<50,    HD, 0, stream>>>(emb0,emb1,emb2,emb3,emb4,emb5, root1, 0, R1eff);
  k_b1t<<<256, 256, 0, stream>>>(W1eff, R1eff, B1t);
  k_tconv<<<256, 256, 0, stream>>>(root2, BtL2, 256, 256, 1280, 0);
  k_tconv<<<1024, 256, 0, stream>>>(W2, BtL2, 1024, 256, 1280, 256);
  k_tconv<<<256, 256, 0, stream>>>(g1w, g1wt, 256, 256, 256, 0);

  // ---- CSR build (counts -> scan -> bin) ----
  k_cnt<<<(NE+255)/256, 256, 0, stream>>>(ei, et, cnt);
  k_scan1<<<SC_NB, SC_T, 0, stream>>>(cnt, bsum);
  k_scan2<<<1, 256, 0, stream>>>(bsum, boff, offs);
  k_scan3<<<SC_NB, SC_T, 0, stream>>>(cnt, boff, offs, cursor);
  k_bin<<<(NE+255)/256, 256, 0, stream>>>(ei, et, cursor, esrc);

  // ---- A1 from CSR gather ----
  k_buildseg<<<NN, 256, 0, stream>>>(x, offs, esrc, A1);

  // ---- per-graph offsets (independent) ----
  k_goffs<<<(NN+255)/256, 256, 0, stream>>>(batch, goffs);

  // ---- layer 1 GEMM: h1 = sigmoid(A1 @ B1 + b1) ----
  dim3 gFull(2, (NN+127)/128);
  k_mfma<8,0,true><<<gFull, 512, 0, stream>>>(A1, 256, nullptr, 0, B1t, b1, h1, NN);

  // ---- layer 2: chunked agg + dual-A K=1280 GEMM ([h1 | agg] @ [root2;W2]) + sigmoid ----
  for (int c0 = 0; c0 < NN; c0 += CHUNK){
    int m = min(CHUNK, NN - c0);
    k_agg<<<(m*64+255)/256, 256, 0, stream>>>(offs, esrc, h1, agg, c0, m);
    dim3 gC(2, (m+127)/128);
    k_mfma<8,32,true><<<gC, 512, 0, stream>>>(h1 + (size_t)c0*HD, 256, agg, NR*HD,
                                              BtL2, b2, hRes + (size_t)c0*HD, m);
  }
  // hRes = h2 (bf16)

  // ---- gate linear: g = h2 @ g1w + g1b (bf16 out), BN stats ----
  k_mfma<8,0,false><<<gFull, 512, 0, stream>>>(hRes, 256, nullptr, 0, g1wt, g1b, g, NN);
  k_bnstats<<<(NN+127)/128, HD, 0, stream>>>(g, chan);
  k_bnfin<<<1, HD, 0, stream>>>(chan, bng, bnb, bnp);

  // ---- gate scalar (no atomics) + fused per-graph softmax/pool/output ----
  k_gate<<<(NN+3)/4, 256, 0, stream>>>(g, bnp, g2w, g2b, gate);
  k_poolg<<<NBATCH, 256, 0, stream>>>(hRes, gate, goffs, glw, glb, out);
}

// Round 12
// 688.294 us; speedup vs baseline: 1.1227x; 1.0235x over previous
//
#include <hip/hip_runtime.h>
#include <hip/hip_bf16.h>
#include <cstdint>

#define NN 50000      // nodes
#define NE 500000     // edges
#define NR 4          // relations
#define NBATCH 512    // graphs
#define HD 256        // hidden/out width
#define NSEG (NN*NR)  // 200000 (dst,rel) segments

__constant__ int c_off[6] = {0,33,38,41,45,47};   // cumulative CARD offsets (total 50)

__device__ __forceinline__ float sigf(float x){ return 1.0f/(1.0f+__expf(-x)); }
__device__ __forceinline__ float bf2f(unsigned short b){ return __uint_as_float((unsigned)b<<16); }
__device__ __forceinline__ unsigned short f2bf(float f){
  unsigned u = __float_as_uint(f);
  return (unsigned short)((u + 0x7fffu + ((u>>16)&1u)) >> 16);   // RNE
}

typedef short bf16raw8 __attribute__((ext_vector_type(8)));
typedef float f32x4v  __attribute__((ext_vector_type(4)));
union LD16 { uint4 u; bf16raw8 v; };

// ---------- folded weight precompute (fp32):  out[rc][h] = emb_j[cl] . W[r, j*64.. , h] ----------
__global__ void k_weff(const float* __restrict__ e0,const float* __restrict__ e1,
                       const float* __restrict__ e2,const float* __restrict__ e3,
                       const float* __restrict__ e4,const float* __restrict__ e5,
                       const float* __restrict__ W, int rstride,
                       float* __restrict__ out){
  int rc = blockIdx.x, h = threadIdx.x;
  int r = rc/50, cg = rc%50;
  int j, cl;
  if      (cg>=47){j=5;cl=cg-47;} else if (cg>=45){j=4;cl=cg-45;}
  else if (cg>=41){j=3;cl=cg-41;} else if (cg>=38){j=2;cl=cg-38;}
  else if (cg>=33){j=1;cl=cg-33;} else            {j=0;cl=cg;}
  const float* emb = j==0?e0:j==1?e1:j==2?e2:j==3?e3:j==4?e4:e5;
  const float* wb = W + (size_t)r*rstride + (size_t)(j*64)*HD + h;
  float acc = 0.f;
  #pragma unroll 8
  for (int k=0;k<64;k++) acc += emb[cl*64+k]*wb[(size_t)k*HD];
  out[(size_t)rc*HD+h] = acc;
}

// ---------- segment counts only ----------
__global__ void k_cnt(const int* __restrict__ ei, const int* __restrict__ et,
                      int* __restrict__ cnt){
  int e = blockIdx.x*256 + threadIdx.x;
  if (e >= NE) return;
  atomicAdd(&cnt[ei[NE+e]*NR + et[e]], 1);
}

// ---------- B1t[o][k] bf16 from W1eff(200 rows)+R1eff(50 rows), zero-padded to 256 ----------
__global__ void k_b1t(const float* __restrict__ W1eff, const float* __restrict__ R1eff,
                      unsigned short* __restrict__ B1t){
  int id = blockIdx.x*256 + threadIdx.x;      // 256*256 total
  int k = id & 255, o = id >> 8;
  float v = 0.f;
  if (k < 200) v = W1eff[(size_t)k*HD + o];
  else if (k < 250) v = R1eff[(size_t)(k-200)*HD + o];
  B1t[(size_t)o*256 + k] = f2bf(v);
}

// ---------- transpose+convert fp32 W[K][O] -> bf16 Wt[o][k] (row stride 256) ----------
__global__ void k_tconv(const float* __restrict__ W, unsigned short* __restrict__ Wt,
                        int K, int O){
  int id = blockIdx.x*256 + threadIdx.x;
  if (id >= K*O) return;
  int k = id % K, o = id / K;
  Wt[(size_t)o*256 + k] = f2bf(W[(size_t)k*O + o]);
}

// ---------- 3-kernel exclusive prefix scan over cnt[NSEG] ----------
#define SC_T 256
#define SC_NB ((NSEG/4 + SC_T - 1)/SC_T)   // 196 blocks

__global__ void k_scan1(const int* __restrict__ cnt, int* __restrict__ bsum){
  __shared__ int sh[SC_T];
  int b = blockIdx.x, t = threadIdx.x;
  int i4 = b*SC_T + t;
  int s = 0;
  if (i4 < NSEG/4){ int4 v = ((const int4*)cnt)[i4]; s = v.x+v.y+v.z+v.w; }
  sh[t] = s; __syncthreads();
  for (int o=128;o>0;o>>=1){ if (t<o) sh[t]+=sh[t+o]; __syncthreads(); }
  if (t==0) bsum[b] = sh[0];
}

__global__ void k_scan2(const int* __restrict__ bsum, int* __restrict__ boff,
                        int* __restrict__ offs){
  __shared__ int sh[256];
  int t = threadIdx.x;
  int v = (t < SC_NB) ? bsum[t] : 0;
  sh[t] = v; __syncthreads();
  for (int o=1;o<256;o<<=1){
    int add = (t>=o) ? sh[t-o] : 0; __syncthreads();
    sh[t] += add; __syncthreads();
  }
  if (t < SC_NB) boff[t] = sh[t] - v;
  if (t == 255) offs[NSEG] = sh[255];
}

__global__ void k_scan3(const int* __restrict__ cnt, const int* __restrict__ boff,
                        int* __restrict__ offs, int* __restrict__ cursor){
  __shared__ int sh[SC_T];
  int b = blockIdx.x, t = threadIdx.x;
  int i4 = b*SC_T + t;
  int4 v = {0,0,0,0};
  if (i4 < NSEG/4) v = ((const int4*)cnt)[i4];
  int s = v.x+v.y+v.z+v.w;
  sh[t] = s; __syncthreads();
  for (int o=1;o<256;o<<=1){
    int add = (t>=o) ? sh[t-o] : 0; __syncthreads();
    sh[t] += add; __syncthreads();
  }
  if (i4 < NSEG/4){
    int excl = sh[t] - s + boff[b];
    int4 ov; ov.x = excl; ov.y = ov.x+v.x; ov.z = ov.y+v.y; ov.w = ov.z+v.z;
    ((int4*)offs)[i4] = ov; ((int4*)cursor)[i4] = ov;   // cursor may alias cnt (read v first)
  }
}

// ---------- bin edges into CSR slots by (dst,rel) ----------
__global__ void k_bin(const int* __restrict__ ei, const int* __restrict__ et,
                      int* __restrict__ cursor, int* __restrict__ esrc){
  int e = blockIdx.x*256 + threadIdx.x;
  if (e >= NE) return;
  int s = ei[e], d = ei[NE+e], t = et[e];
  int slot = atomicAdd(&cursor[d*NR + t], 1);
  esrc[slot] = s;
}

// ---------- A1[n][256] from CSR gather:
//            t<200: (r,bin) count/cnt ; t in [200,250): root one-hot ; else 0 ----------
__global__ void k_buildseg(const int* __restrict__ x, const int* __restrict__ offs,
                           const int* __restrict__ esrc, unsigned short* __restrict__ A1){
  int n = blockIdx.x, t = threadIdx.x;
  float v = 0.f;
  if (t < 200){
    int r = t/50, bin = t%50;
    int j, cl;
    if      (bin>=47){j=5;cl=bin-47;} else if (bin>=45){j=4;cl=bin-45;}
    else if (bin>=41){j=3;cl=bin-41;} else if (bin>=38){j=2;cl=bin-38;}
    else if (bin>=33){j=1;cl=bin-33;} else            {j=0;cl=bin;}
    int a = offs[n*NR+r], e2 = offs[n*NR+r+1];
    int c = 0;
    for (int e=a;e<e2;e++){
      int s = esrc[e];
      c += (x[s*6+j] == cl) ? 1 : 0;
    }
    v = (float)c / (float)max(e2-a, 1);
  } else if (t < 250){
    int cg = t - 200;
    #pragma unroll
    for (int j=0;j<6;j++) if (cg == c_off[j] + x[n*6+j]) v = 1.f;
  }
  A1[(size_t)n*256 + t] = f2bf(v);
}

// ---------- bf16 MFMA GEMM, no LDS, K=256, split output, 8-wave + 2-deep pipeline ----------
// C[M,N] = A[M,256] @ Bt[N,256]^T (+bias)(+sigmoid); cols<n0 -> out0(ldc0) else out1(ldc1)
// block = 512 thr = 8 waves (4x2), block tile 128x128, wave tile 32x64 (2x4 frags 16x16x32)
template<bool SIG>
__global__ __launch_bounds__(512) void k_mfma(
    const unsigned short* __restrict__ A,  int lda,
    const unsigned short* __restrict__ Bt,       // [N][256] bf16
    const float* __restrict__ bias,              // [N] or null
    unsigned short* __restrict__ out0, int ldc0, int n0,
    unsigned short* __restrict__ out1, int ldc1,
    int M){
  constexpr int NK = 8;
  constexpr int K  = 256;
  int tid = threadIdx.x;
  int wave = tid >> 6, lane = tid & 63;
  int wm = (wave >> 1) * 32, wn = (wave & 1) * 64;
  int bm = blockIdx.y * 128, bn = blockIdx.x * 128;
  int lrow = lane & 15, lk8 = (lane >> 4) * 8;

  const unsigned short* aP[2];
  const unsigned short* bP[4];
  #pragma unroll
  for (int mi=0;mi<2;mi++){
    int row = bm + wm + mi*16 + lrow; if (row > M-1) row = M-1;
    aP[mi] = A + (size_t)row*lda + lk8;
  }
  #pragma unroll
  for (int nj=0;nj<4;nj++){
    int col = bn + wn + nj*16 + lrow;
    bP[nj] = Bt + (size_t)col*K + lk8;
  }

  f32x4v acc[2][4] = {};
  bf16raw8 aF[2][2], bF[2][4];

  #pragma unroll
  for (int mi=0;mi<2;mi++){ LD16 t; t.u = *(const uint4*)(aP[mi]); aF[0][mi]=t.v; }
  #pragma unroll
  for (int nj=0;nj<4;nj++){ LD16 t; t.u = *(const uint4*)(bP[nj]); bF[0][nj]=t.v; }

  #pragma unroll
  for (int k=0;k<NK;k++){
    int cur = k & 1, nxt = cur ^ 1;
    if (k+1 < NK){
      #pragma unroll
      for (int mi=0;mi<2;mi++){ LD16 t; t.u = *(const uint4*)(aP[mi] + (k+1)*32); aF[nxt][mi]=t.v; }
      #pragma unroll
      for (int nj=0;nj<4;nj++){ LD16 t; t.u = *(const uint4*)(bP[nj] + (k+1)*32); bF[nxt][nj]=t.v; }
    }
    #pragma unroll
    for (int mi=0;mi<2;mi++)
      #pragma unroll
      for (int nj=0;nj<4;nj++)
        acc[mi][nj] = __builtin_amdgcn_mfma_f32_16x16x32_bf16(aF[cur][mi], bF[cur][nj], acc[mi][nj], 0, 0, 0);
  }

  int r0 = (lane >> 4) * 4;
  #pragma unroll
  for (int mi = 0; mi < 2; mi++){
    #pragma unroll
    for (int i = 0; i < 4; i++){
      int row = bm + wm + mi*16 + r0 + i;
      if (row >= M) continue;
      #pragma unroll
      for (int nj = 0; nj < 4; nj++){
        int col = bn + wn + nj*16 + lrow;
        float v = acc[mi][nj][i];
        if (bias) v += bias[col];
        if (SIG) v = sigf(v);
        if (col < n0) out0[(size_t)row*ldc0 + col] = f2bf(v);
        else          out1[(size_t)row*ldc1 + (col - n0)] = f2bf(v);
      }
    }
  }
}

// ---------- combine pass 1: pacc[n] = sum_{r=0,1} mean_e z[src_e][r*256:c] ----------
__global__ void k_comb1(const int* __restrict__ offs, const int* __restrict__ esrc,
                        const unsigned short* __restrict__ zbuf,
                        unsigned short* __restrict__ pacc){
  int gid = blockIdx.x*256 + threadIdx.x;
  int n = gid >> 6;
  if (n >= NN) return;
  int lane = gid & 63;
  float t0=0.f,t1=0.f,t2=0.f,t3=0.f;
  #pragma unroll
  for (int r=0;r<2;r++){
    int a = offs[n*NR+r], b = offs[n*NR+r+1];
    float a0=0.f,a1=0.f,a2=0.f,a3=0.f;
    for (int e=a;e<b;e++){
      int s = esrc[e];
      ushort4 v = *(const ushort4*)(zbuf + (size_t)s*512 + r*256 + lane*4);
      a0+=bf2f(v.x); a1+=bf2f(v.y); a2+=bf2f(v.z); a3+=bf2f(v.w);
    }
    float iv = 1.0f / (float)max(b-a, 1);
    t0+=a0*iv; t1+=a1*iv; t2+=a2*iv; t3+=a3*iv;
  }
  ushort4 o; o.x=f2bf(t0); o.y=f2bf(t1); o.z=f2bf(t2); o.w=f2bf(t3);
  *(ushort4*)(pacc + (size_t)n*HD + lane*4) = o;
}

// ---------- combine pass 2: h2[n] = sigmoid(b2 + root[n] + pacc[n] + sum_{r=2,3} mean_e z[src_e]) ----------
__global__ void k_comb2(const int* __restrict__ offs, const int* __restrict__ esrc,
                        const unsigned short* __restrict__ zbuf,
                        const unsigned short* __restrict__ pacc,
                        const unsigned short* __restrict__ rootbuf,
                        const float* __restrict__ b2,
                        unsigned short* __restrict__ h2){
  int gid = blockIdx.x*256 + threadIdx.x;
  int n = gid >> 6;
  if (n >= NN) return;
  int lane = gid & 63;
  float t0=0.f,t1=0.f,t2=0.f,t3=0.f;
  #pragma unroll
  for (int r=0;r<2;r++){
    int a = offs[n*NR+2+r], b = offs[n*NR+2+r+1];
    float a0=0.f,a1=0.f,a2=0.f,a3=0.f;
    for (int e=a;e<b;e++){
      int s = esrc[e];
      ushort4 v = *(const ushort4*)(zbuf + (size_t)s*512 + r*256 + lane*4);
      a0+=bf2f(v.x); a1+=bf2f(v.y); a2+=bf2f(v.z); a3+=bf2f(v.w);
    }
    float iv = 1.0f / (float)max(b-a, 1);
    t0+=a0*iv; t1+=a1*iv; t2+=a2*iv; t3+=a3*iv;
  }
  ushort4 p = *(const ushort4*)(pacc + (size_t)n*HD + lane*4);
  ushort4 rt= *(const ushort4*)(rootbuf + (size_t)n*HD + lane*4);
  float4 bb = *(const float4*)(b2 + lane*4);
  ushort4 o;
  o.x = f2bf(sigf(t0 + bf2f(p.x) + bf2f(rt.x) + bb.x));
  o.y = f2bf(sigf(t1 + bf2f(p.y) + bf2f(rt.y) + bb.y));
  o.z = f2bf(sigf(t2 + bf2f(p.z) + bf2f(rt.z) + bb.z));
  o.w = f2bf(sigf(t3 + bf2f(p.w) + bf2f(rt.w) + bb.w));
  *(ushort4*)(h2 + (size_t)n*HD + lane*4) = o;
}

// ---------- BN stats over bf16 g (training-mode, biased var) ----------
__global__ void k_bnstats(const unsigned short* __restrict__ g, float* __restrict__ chan){
  int c = threadIdx.x;
  int r0 = blockIdx.x*128;
  int rend = min(r0+128, NN);
  float s=0.f, q=0.f;
  for (int row=r0; row<rend; row++){
    float v = bf2f(g[(size_t)row*HD + c]);
    s += v; q += v*v;
  }
  atomicAdd(&chan[c], s); atomicAdd(&chan[HD+c], q);
}

__global__ void k_bnfin(const float* __restrict__ chan, const float* __restrict__ bng,
                        const float* __restrict__ bnb, float* __restrict__ bnp){
  int c = threadIdx.x;
  float mu = chan[c]/(float)NN;
  float var = chan[HD+c]/(float)NN - mu*mu;
  float scale = bng[c]*rsqrtf(var + 1e-5f);
  bnp[c] = bnb[c] - mu*scale;     // shift
  bnp[HD+c] = scale;              // scale
}

// ---------- gate[n] = relu(BN(g[n])) . g2_w + g2_b (no atomics, bf16 g) ----------
__global__ void k_gate(const unsigned short* __restrict__ g, const float* __restrict__ bnp,
                       const float* __restrict__ g2w, const float* __restrict__ g2b,
                       float* __restrict__ gate){
  int lane = threadIdx.x & 63;
  int n = blockIdx.x*4 + (threadIdx.x>>6);
  if (n >= NN) return;
  float s = 0.f;
  #pragma unroll
  for (int k=0;k<4;k++){
    int c = lane + k*64;
    float v = bf2f(g[(size_t)n*HD + c])*bnp[HD+c] + bnp[c];
    v = fmaxf(v, 0.f);
    s += v * g2w[c];
  }
  #pragma unroll
  for (int o=32;o>0;o>>=1) s += __shfl_down(s, o);
  if (lane==0) gate[n] = s + g2b[0];
}

// ---------- per-graph offsets from SORTED batch ----------
__global__ void k_goffs(const int* __restrict__ batch, int* __restrict__ goffs){
  int n = blockIdx.x*256 + threadIdx.x;
  if (n >= NN) return;
  int b = batch[n];
  int prev = (n == 0) ? -1 : batch[n-1];
  for (int gg = prev+1; gg <= b; gg++) goffs[gg] = n;
  if (n == NN-1){ for (int gg = b+1; gg <= NBATCH; gg++) goffs[gg] = NN; }
}

// ---------- fused per-graph: softmax(gate) -> weighted pool of h2 -> out = sigmoid(.glw+glb) ----------
__global__ __launch_bounds__(256) void k_poolg(
    const unsigned short* __restrict__ h2, const float* __restrict__ gate,
    const int* __restrict__ goffs, const float* __restrict__ glw,
    const float* __restrict__ glb, float* __restrict__ out){
  __shared__ float red[256];
  int b = blockIdx.x, tid = threadIdx.x;
  int a = goffs[b], e = goffs[b+1];

  float m = -3.4e38f;
  for (int n = a + tid; n < e; n += 256) m = fmaxf(m, gate[n]);
  red[tid] = m; __syncthreads();
  for (int o = 128; o > 0; o >>= 1){ if (tid < o) red[tid] = fmaxf(red[tid], red[tid+o]); __syncthreads(); }
  m = red[0]; __syncthreads();

  float s = 0.f;
  for (int n = a + tid; n < e; n += 256) s += __expf(gate[n] - m);
  red[tid] = s; __syncthreads();
  for (int o = 128; o > 0; o >>= 1){ if (tid < o) red[tid] += red[tid+o]; __syncthreads(); }
  float denom = red[0] + 1e-16f; __syncthreads();

  float acc = 0.f;
  #pragma unroll 4
  for (int n = a; n < e; n++){
    float ev = __expf(gate[n] - m);
    acc += ev * bf2f(h2[(size_t)n*HD + tid]);
  }
  acc /= denom;

  red[tid] = acc * glw[tid]; __syncthreads();
  for (int o = 128; o > 0; o >>= 1){ if (tid < o) red[tid] += red[tid+o]; __syncthreads(); }
  if (tid == 0) out[b] = sigf(red[0] + glb[0]);
}

extern "C" void kernel_launch(void* const* d_in, const int* in_sizes, int n_in,
                              void* d_out, int out_size, void* d_ws, size_t ws_size,
                              hipStream_t stream) {
  const int* x     = (const int*)d_in[0];
  const int* ei    = (const int*)d_in[1];
  const int* et    = (const int*)d_in[2];
  const int* batch = (const int*)d_in[3];
  const float* emb0 = (const float*)d_in[4];
  const float* emb1 = (const float*)d_in[5];
  const float* emb2 = (const float*)d_in[6];
  const float* emb3 = (const float*)d_in[7];
  const float* emb4 = (const float*)d_in[8];
  const float* emb5 = (const float*)d_in[9];
  const float* W1    = (const float*)d_in[10];
  const float* root1 = (const float*)d_in[11];
  const float* b1    = (const float*)d_in[12];
  const float* W2    = (const float*)d_in[13];  // [R,H,O] flat == [1024,256]
  const float* root2 = (const float*)d_in[14];
  const float* b2    = (const float*)d_in[15];
  const float* g1w   = (const float*)d_in[16];
  const float* g1b   = (const float*)d_in[17];
  const float* bng   = (const float*)d_in[18];
  const float* bnb   = (const float*)d_in[19];
  const float* g2w   = (const float*)d_in[20];
  const float* g2b   = (const float*)d_in[21];
  const float* glw   = (const float*)d_in[22];
  const float* glb   = (const float*)d_in[23];
  float* out = (float*)d_out;

  // ---- workspace carve-up (256B aligned), total ≈ 133 MB ----
  char* w = (char*)d_ws;
  auto alloc = [&](size_t bytes)->char* {
    char* p = w; w += (bytes + 255) & ~(size_t)255; return p;
  };
  // slotA: A1 -> rootbuf -> g   (25.6 MB)
  char* slotA = alloc((size_t)NN*HD*2);
  unsigned short* A1      = (unsigned short*)slotA;
  unsigned short* rootbuf = (unsigned short*)slotA;
  unsigned short* g       = (unsigned short*)slotA;
  // slotH: h1 -> h2             (25.6 MB)
  unsigned short* h1 = (unsigned short*)alloc((size_t)NN*HD*2);
  unsigned short* h2 = h1;
  // slotZ: zbuf (both passes)   (51.2 MB)
  unsigned short* zbuf = (unsigned short*)alloc((size_t)NN*512*2);
  // pacc                        (25.6 MB)
  unsigned short* pacc = (unsigned short*)alloc((size_t)NN*HD*2);
  int*   cnt  = (int*)alloc((size_t)NSEG*sizeof(int));
  int*   cursor = cnt;   // scan3 reads cnt then writes cursor: alias-safe
  int*   offs = (int*)alloc((size_t)(NSEG+1)*sizeof(int));
  int*   bsum = (int*)alloc((size_t)SC_NB*sizeof(int));
  int*   boff = (int*)alloc((size_t)SC_NB*sizeof(int));
  int*   esrc = (int*)alloc((size_t)NE*sizeof(int));
  float* W1eff= (float*)alloc((size_t)200*HD*sizeof(float));
  float* R1eff= (float*)alloc((size_t)50*HD*sizeof(float));
  unsigned short* B1t  = (unsigned short*)alloc((size_t)256*256*2);
  unsigned short* Btz1 = (unsigned short*)alloc((size_t)768*256*2);  // [W2_0;W2_1;root2]^T
  unsigned short* Btz2 = (unsigned short*)alloc((size_t)512*256*2);  // [W2_2;W2_3]^T
  unsigned short* g1wt = (unsigned short*)alloc((size_t)256*256*2);
  float* gate = (float*)alloc((size_t)NN*sizeof(float));
  int*   goffs= (int*)alloc((size_t)(NBATCH+1)*sizeof(int));
  float* chan = (float*)alloc((size_t)2*HD*sizeof(float));
  float* bnp  = (float*)alloc((size_t)2*HD*sizeof(float));

  // ---- zero init ----
  hipMemsetAsync(cnt,  0, (size_t)NSEG*sizeof(int), stream);
  hipMemsetAsync(chan, 0, (size_t)2*HD*sizeof(float), stream);

  // ---- folded layer-1 weights, bf16 transposed weight assembly ----
  k_weff<<<NR*50, HD, 0, stream>>>(emb0,emb1,emb2,emb3,emb4,emb5, W1, 384*HD, W1eff);
  k_weff<<<50,    HD, 0, stream>>>(emb0,emb1,emb2,emb3,emb4,emb5, root1, 0, R1eff);
  k_b1t<<<256, 256, 0, stream>>>(W1eff, R1eff, B1t);
  k_tconv<<<256, 256, 0, stream>>>(W2,               Btz1,           256, 256);
  k_tconv<<<256, 256, 0, stream>>>(W2 + 256*256,     Btz1 + 256*256, 256, 256);
  k_tconv<<<256, 256, 0, stream>>>(root2,            Btz1 + 512*256, 256, 256);
  k_tconv<<<256, 256, 0, stream>>>(W2 + 2*256*256,   Btz2,           256, 256);
  k_tconv<<<256, 256, 0, stream>>>(W2 + 3*256*256,   Btz2 + 256*256, 256, 256);
  k_tconv<<<256, 256, 0, stream>>>(g1w,              g1wt,           256, 256);

  // ---- CSR build (counts -> scan -> bin) ----
  k_cnt<<<(NE+255)/256, 256, 0, stream>>>(ei, et, cnt);
  k_scan1<<<SC_NB, SC_T, 0, stream>>>(cnt, bsum);
  k_scan2<<<1, 256, 0, stream>>>(bsum, boff, offs);
  k_scan3<<<SC_NB, SC_T, 0, stream>>>(cnt, boff, offs, cursor);
  k_bin<<<(NE+255)/256, 256, 0, stream>>>(ei, et, cursor, esrc);

  // ---- A1 from CSR gather ----
  k_buildseg<<<NN, 256, 0, stream>>>(x, offs, esrc, A1);

  // ---- per-graph offsets (independent) ----
  k_goffs<<<(NN+255)/256, 256, 0, stream>>>(batch, goffs);

  // ---- layer 1 GEMM: h1 = sigmoid(A1 @ B1 + b1)   grid (2,391) ----
  dim3 g256(2, (NN+127)/128);
  k_mfma<true><<<g256, 512, 0, stream>>>(A1, 256, B1t, b1, h1, 256, 256, nullptr, 0, NN);

  // ---- z pass 1: [z_r0|z_r1|root] = h1 @ Btz1^T   grid (6,391); root -> slotA (A1 dead) ----
  dim3 g768(6, (NN+127)/128);
  k_mfma<false><<<g768, 512, 0, stream>>>(h1, 256, Btz1, nullptr, zbuf, 512, 512, rootbuf, 256, NN);
  k_comb1<<<(NN*64+255)/256, 256, 0, stream>>>(offs, esrc, zbuf, pacc);

  // ---- z pass 2: [z_r2|z_r3] = h1 @ Btz2^T        grid (4,391) ----
  dim3 g512(4, (NN+127)/128);
  k_mfma<false><<<g512, 512, 0, stream>>>(h1, 256, Btz2, nullptr, zbuf, 512, 512, nullptr, 0, NN);
  k_comb2<<<(NN*64+255)/256, 256, 0, stream>>>(offs, esrc, zbuf, pacc, rootbuf, b2, h2); // h2 over h1 (dead)

  // ---- gate linear: g = h2 @ g1w + g1b (bf16, over rootbuf: dead) ----
  k_mfma<false><<<g256, 512, 0, stream>>>(h2, 256, g1wt, g1b, g, 256, 256, nullptr, 0, NN);
  k_bnstats<<<(NN+127)/128, HD, 0, stream>>>(g, chan);
  k_bnfin<<<1, HD, 0, stream>>>(chan, bng, bnb, bnp);

  // ---- gate scalar + fused per-graph softmax/pool/output ----
  k_gate<<<(NN+3)/4, 256, 0, stream>>>(g, bnp, g2w, g2b, gate);
  k_poolg<<<NBATCH, 256, 0, stream>>>(h2, gate, goffs, glw, glb, out);
}

// Round 14
// 658.053 us; speedup vs baseline: 1.1743x; 1.0460x over previous
//
#include <hip/hip_runtime.h>
#include <hip/hip_bf16.h>
#include <cstdint>

#define NN 50000      // nodes
#define NE 500000     // edges
#define NR 4          // relations
#define NBATCH 512    // graphs
#define HD 256        // hidden/out width
#define NSEG (NN*NR)  // 200000 (dst,rel) segments

__constant__ int c_off[6] = {0,33,38,41,45,47};   // cumulative CARD offsets (total 50)

__device__ __forceinline__ float sigf(float x){ return 1.0f/(1.0f+__expf(-x)); }
__device__ __forceinline__ float bf2f(unsigned short b){ return __uint_as_float((unsigned)b<<16); }
__device__ __forceinline__ unsigned short f2bf(float f){
  unsigned u = __float_as_uint(f);
  return (unsigned short)((u + 0x7fffu + ((u>>16)&1u)) >> 16);   // RNE
}

typedef short bf16raw8 __attribute__((ext_vector_type(8)));
typedef float f32x4v  __attribute__((ext_vector_type(4)));
union LD16 { uint4 u; bf16raw8 v; };

// ---------- folded weight precompute (fp32):  out[rc][h] = emb_j[cl] . W[r, j*64.. , h] ----------
__global__ void k_weff(const float* __restrict__ e0,const float* __restrict__ e1,
                       const float* __restrict__ e2,const float* __restrict__ e3,
                       const float* __restrict__ e4,const float* __restrict__ e5,
                       const float* __restrict__ W, int rstride,
                       float* __restrict__ out){
  int rc = blockIdx.x, h = threadIdx.x;
  int r = rc/50, cg = rc%50;
  int j, cl;
  if      (cg>=47){j=5;cl=cg-47;} else if (cg>=45){j=4;cl=cg-45;}
  else if (cg>=41){j=3;cl=cg-41;} else if (cg>=38){j=2;cl=cg-38;}
  else if (cg>=33){j=1;cl=cg-33;} else            {j=0;cl=cg;}
  const float* emb = j==0?e0:j==1?e1:j==2?e2:j==3?e3:j==4?e4:e5;
  const float* wb = W + (size_t)r*rstride + (size_t)(j*64)*HD + h;
  float acc = 0.f;
  #pragma unroll 8
  for (int k=0;k<64;k++) acc += emb[cl*64+k]*wb[(size_t)k*HD];
  out[(size_t)rc*HD+h] = acc;
}

// ---------- segment counts only ----------
__global__ void k_cnt(const int* __restrict__ ei, const int* __restrict__ et,
                      int* __restrict__ cnt){
  int e = blockIdx.x*256 + threadIdx.x;
  if (e >= NE) return;
  atomicAdd(&cnt[ei[NE+e]*NR + et[e]], 1);
}

// ---------- B1t[o][k] bf16 from W1eff(200 rows)+R1eff(50 rows), zero-padded to 256 ----------
__global__ void k_b1t(const float* __restrict__ W1eff, const float* __restrict__ R1eff,
                      unsigned short* __restrict__ B1t){
  int id = blockIdx.x*256 + threadIdx.x;      // 256*256 total
  int k = id & 255, o = id >> 8;
  float v = 0.f;
  if (k < 200) v = W1eff[(size_t)k*HD + o];
  else if (k < 250) v = R1eff[(size_t)(k-200)*HD + o];
  B1t[(size_t)o*256 + k] = f2bf(v);
}

// ---------- transpose+convert fp32 W[K][O] -> bf16 Wt[o][k] (row stride 256) ----------
__global__ void k_tconv(const float* __restrict__ W, unsigned short* __restrict__ Wt,
                        int K, int O){
  int id = blockIdx.x*256 + threadIdx.x;
  if (id >= K*O) return;
  int k = id % K, o = id / K;
  Wt[(size_t)o*256 + k] = f2bf(W[(size_t)k*O + o]);
}

// ---------- 3-kernel exclusive prefix scan over cnt[NSEG] ----------
#define SC_T 256
#define SC_NB ((NSEG/4 + SC_T - 1)/SC_T)   // 196 blocks

__global__ void k_scan1(const int* __restrict__ cnt, int* __restrict__ bsum){
  __shared__ int sh[SC_T];
  int b = blockIdx.x, t = threadIdx.x;
  int i4 = b*SC_T + t;
  int s = 0;
  if (i4 < NSEG/4){ int4 v = ((const int4*)cnt)[i4]; s = v.x+v.y+v.z+v.w; }
  sh[t] = s; __syncthreads();
  for (int o=128;o>0;o>>=1){ if (t<o) sh[t]+=sh[t+o]; __syncthreads(); }
  if (t==0) bsum[b] = sh[0];
}

__global__ void k_scan2(const int* __restrict__ bsum, int* __restrict__ boff,
                        int* __restrict__ offs){
  __shared__ int sh[256];
  int t = threadIdx.x;
  int v = (t < SC_NB) ? bsum[t] : 0;
  sh[t] = v; __syncthreads();
  for (int o=1;o<256;o<<=1){
    int add = (t>=o) ? sh[t-o] : 0; __syncthreads();
    sh[t] += add; __syncthreads();
  }
  if (t < SC_NB) boff[t] = sh[t] - v;
  if (t == 255) offs[NSEG] = sh[255];
}

__global__ void k_scan3(const int* __restrict__ cnt, const int* __restrict__ boff,
                        int* __restrict__ offs, int* __restrict__ cursor){
  __shared__ int sh[SC_T];
  int b = blockIdx.x, t = threadIdx.x;
  int i4 = b*SC_T + t;
  int4 v = {0,0,0,0};
  if (i4 < NSEG/4) v = ((const int4*)cnt)[i4];
  int s = v.x+v.y+v.z+v.w;
  sh[t] = s; __syncthreads();
  for (int o=1;o<256;o<<=1){
    int add = (t>=o) ? sh[t-o] : 0; __syncthreads();
    sh[t] += add; __syncthreads();
  }
  if (i4 < NSEG/4){
    int excl = sh[t] - s + boff[b];
    int4 ov; ov.x = excl; ov.y = ov.x+v.x; ov.z = ov.y+v.y; ov.w = ov.z+v.z;
    ((int4*)offs)[i4] = ov; ((int4*)cursor)[i4] = ov;   // cursor may alias cnt (read v first)
  }
}

// ---------- bin edges into CSR slots by (dst,rel) ----------
__global__ void k_bin(const int* __restrict__ ei, const int* __restrict__ et,
                      int* __restrict__ cursor, int* __restrict__ esrc){
  int e = blockIdx.x*256 + threadIdx.x;
  if (e >= NE) return;
  int s = ei[e], d = ei[NE+e], t = et[e];
  int slot = atomicAdd(&cursor[d*NR + t], 1);
  esrc[slot] = s;
}

// ---------- A1[n][256] from CSR gather ----------
__global__ void k_buildseg(const int* __restrict__ x, const int* __restrict__ offs,
                           const int* __restrict__ esrc, unsigned short* __restrict__ A1){
  int n = blockIdx.x, t = threadIdx.x;
  float v = 0.f;
  if (t < 200){
    int r = t/50, bin = t%50;
    int j, cl;
    if      (bin>=47){j=5;cl=bin-47;} else if (bin>=45){j=4;cl=bin-45;}
    else if (bin>=41){j=3;cl=bin-41;} else if (bin>=38){j=2;cl=bin-38;}
    else if (bin>=33){j=1;cl=bin-33;} else            {j=0;cl=bin;}
    int a = offs[n*NR+r], e2 = offs[n*NR+r+1];
    int c = 0;
    for (int e=a;e<e2;e++){
      int s = esrc[e];
      c += (x[s*6+j] == cl) ? 1 : 0;
    }
    v = (float)c / (float)max(e2-a, 1);
  } else if (t < 250){
    int cg = t - 200;
    #pragma unroll
    for (int j=0;j<6;j++) if (cg == c_off[j] + x[n*6+j]) v = 1.f;
  }
  A1[(size_t)n*256 + t] = f2bf(v);
}

// ---------- bf16 MFMA GEMM: LDS-staged 128x128 tile, BK=64 double-buffer, XOR swizzle ----------
// C[M,N] = A[M,256] @ Bt[N,256]^T (+bias)(+sigmoid); cols<n0 -> out0(ldc0) else out1(ldc1)
// block = 256 thr = 4 waves (2x2), wave tile 64x64 (4x4 frags 16x16x32). K fixed 256.
template<bool SIG>
__global__ __launch_bounds__(256) void k_mfma(
    const unsigned short* __restrict__ A,  int lda,
    const unsigned short* __restrict__ Bt,       // [N][256] bf16
    const float* __restrict__ bias,              // [N] or null
    unsigned short* __restrict__ out0, int ldc0, int n0,
    unsigned short* __restrict__ out1, int ldc1,
    int M){
  constexpr int NT = 4;                 // 256 / BK(64)
  __shared__ unsigned short lds[2][2][128*64];   // [buf][A/B][row*64 + k] = 64 KB
  int tid = threadIdx.x;
  int wave = tid >> 6, lane = tid & 63;
  int wm = (wave >> 1) * 64, wn = (wave & 1) * 64;
  int bm = blockIdx.y * 128, bn = blockIdx.x * 128;
  int lrow = lane & 15, q = lane >> 4;

  // staging indices: chunk c = v*256+tid -> row=c>>3, kc=c&7; swizzled pc = kc ^ (row&7)
  uint4 rA[4], rB[4];

  auto load_regs = [&](int kt){
    #pragma unroll
    for (int v=0; v<4; v++){
      int c = v*256 + tid;
      int row = c >> 3, kc = c & 7;
      int ra = bm + row; if (ra > M-1) ra = M-1;
      rA[v] = *(const uint4*)(A  + (size_t)ra*lda + kt*64 + kc*8);
      int cb = bn + row;
      rB[v] = *(const uint4*)(Bt + (size_t)cb*256 + kt*64 + kc*8);
    }
  };
  auto write_lds = [&](int buf){
    #pragma unroll
    for (int v=0; v<4; v++){
      int c = v*256 + tid;
      int row = c >> 3, kc = c & 7;
      int pc = kc ^ (row & 7);
      *(uint4*)&lds[buf][0][row*64 + pc*8] = rA[v];
      *(uint4*)&lds[buf][1][row*64 + pc*8] = rB[v];
    }
  };

  f32x4v acc[4][4] = {};

  load_regs(0); write_lds(0);
  __syncthreads();

  for (int kt=0; kt<NT; ++kt){
    int cur = kt & 1;
    bool pf = (kt+1 < NT);
    if (pf) load_regs(kt+1);
    #pragma unroll
    for (int s=0; s<2; s++){
      bf16raw8 aF[4], bF[4];
      #pragma unroll
      for (int mi=0; mi<4; mi++){
        int row = wm + mi*16 + lrow;
        int pc = (s*4 + q) ^ (row & 7);
        LD16 t; t.u = *(const uint4*)&lds[cur][0][row*64 + pc*8];
        aF[mi] = t.v;
      }
      #pragma unroll
      for (int nj=0; nj<4; nj++){
        int col = wn + nj*16 + lrow;
        int pc = (s*4 + q) ^ (col & 7);
        LD16 t; t.u = *(const uint4*)&lds[cur][1][col*64 + pc*8];
        bF[nj] = t.v;
      }
      #pragma unroll
      for (int mi=0; mi<4; mi++)
        #pragma unroll
        for (int nj=0; nj<4; nj++)
          acc[mi][nj] = __builtin_amdgcn_mfma_f32_16x16x32_bf16(aF[mi], bF[nj], acc[mi][nj], 0, 0, 0);
    }
    if (pf) write_lds(cur ^ 1);
    __syncthreads();
  }

  // ---- epilogue: bias/sigmoid -> bf16 -> LDS C-stage (32 KB in lds[0]) -> coalesced stores ----
  unsigned short* cst = &lds[0][0][0];   // [128][128] ushort
  int r0 = q * 4;
  #pragma unroll
  for (int mi=0; mi<4; mi++){
    #pragma unroll
    for (int i=0; i<4; i++){
      int row = wm + mi*16 + r0 + i;
      #pragma unroll
      for (int nj=0; nj<4; nj++){
        int col = wn + nj*16 + lrow;
        float v = acc[mi][nj][i];
        if (bias) v += bias[bn + col];
        if (SIG)  v = sigf(v);
        cst[row*128 + col] = f2bf(v);
      }
    }
  }
  __syncthreads();
  #pragma unroll
  for (int v=0; v<8; v++){
    int p = v*256 + tid;            // 0..2047 16B-chunks
    int row = p >> 4, cc = p & 15;
    int rg = bm + row;
    if (rg >= M) continue;
    uint4 val = *(const uint4*)&cst[row*128 + cc*8];
    int cg = bn + cc*8;
    if (cg < n0) *(uint4*)(out0 + (size_t)rg*ldc0 + cg)        = val;
    else         *(uint4*)(out1 + (size_t)rg*ldc1 + (cg - n0)) = val;
  }
}

// ---------- combine pass 1: pacc[n] = sum_{r=0,1} mean_e z[src_e][r*256:c] ----------
__global__ void k_comb1(const int* __restrict__ offs, const int* __restrict__ esrc,
                        const unsigned short* __restrict__ zbuf,
                        unsigned short* __restrict__ pacc){
  int gid = blockIdx.x*256 + threadIdx.x;
  int n = gid >> 6;
  if (n >= NN) return;
  int lane = gid & 63;
  float t0=0.f,t1=0.f,t2=0.f,t3=0.f;
  #pragma unroll
  for (int r=0;r<2;r++){
    int a = offs[n*NR+r], b = offs[n*NR+r+1];
    float a0=0.f,a1=0.f,a2=0.f,a3=0.f;
    for (int e=a;e<b;e++){
      int s = esrc[e];
      ushort4 v = *(const ushort4*)(zbuf + (size_t)s*512 + r*256 + lane*4);
      a0+=bf2f(v.x); a1+=bf2f(v.y); a2+=bf2f(v.z); a3+=bf2f(v.w);
    }
    float iv = 1.0f / (float)max(b-a, 1);
    t0+=a0*iv; t1+=a1*iv; t2+=a2*iv; t3+=a3*iv;
  }
  ushort4 o; o.x=f2bf(t0); o.y=f2bf(t1); o.z=f2bf(t2); o.w=f2bf(t3);
  *(ushort4*)(pacc + (size_t)n*HD + lane*4) = o;
}

// ---------- combine pass 2: h2[n] = sigmoid(b2 + root[n] + pacc[n] + sum_{r=2,3} mean_e z[src_e]) ----------
__global__ void k_comb2(const int* __restrict__ offs, const int* __restrict__ esrc,
                        const unsigned short* __restrict__ zbuf,
                        const unsigned short* __restrict__ pacc,
                        const unsigned short* __restrict__ rootbuf,
                        const float* __restrict__ b2,
                        unsigned short* __restrict__ h2){
  int gid = blockIdx.x*256 + threadIdx.x;
  int n = gid >> 6;
  if (n >= NN) return;
  int lane = gid & 63;
  float t0=0.f,t1=0.f,t2=0.f,t3=0.f;
  #pragma unroll
  for (int r=0;r<2;r++){
    int a = offs[n*NR+2+r], b = offs[n*NR+2+r+1];
    float a0=0.f,a1=0.f,a2=0.f,a3=0.f;
    for (int e=a;e<b;e++){
      int s = esrc[e];
      ushort4 v = *(const ushort4*)(zbuf + (size_t)s*512 + r*256 + lane*4);
      a0+=bf2f(v.x); a1+=bf2f(v.y); a2+=bf2f(v.z); a3+=bf2f(v.w);
    }
    float iv = 1.0f / (float)max(b-a, 1);
    t0+=a0*iv; t1+=a1*iv; t2+=a2*iv; t3+=a3*iv;
  }
  ushort4 p = *(const ushort4*)(pacc + (size_t)n*HD + lane*4);
  ushort4 rt= *(const ushort4*)(rootbuf + (size_t)n*HD + lane*4);
  float4 bb = *(const float4*)(b2 + lane*4);
  ushort4 o;
  o.x = f2bf(sigf(t0 + bf2f(p.x) + bf2f(rt.x) + bb.x));
  o.y = f2bf(sigf(t1 + bf2f(p.y) + bf2f(rt.y) + bb.y));
  o.z = f2bf(sigf(t2 + bf2f(p.z) + bf2f(rt.z) + bb.z));
  o.w = f2bf(sigf(t3 + bf2f(p.w) + bf2f(rt.w) + bb.w));
  *(ushort4*)(h2 + (size_t)n*HD + lane*4) = o;
}

// ---------- BN stats over bf16 g (training-mode, biased var) ----------
__global__ void k_bnstats(const unsigned short* __restrict__ g, float* __restrict__ chan){
  int c = threadIdx.x;
  int r0 = blockIdx.x*128;
  int rend = min(r0+128, NN);
  float s=0.f, q=0.f;
  for (int row=r0; row<rend; row++){
    float v = bf2f(g[(size_t)row*HD + c]);
    s += v; q += v*v;
  }
  atomicAdd(&chan[c], s); atomicAdd(&chan[HD+c], q);
}

__global__ void k_bnfin(const float* __restrict__ chan, const float* __restrict__ bng,
                        const float* __restrict__ bnb, float* __restrict__ bnp){
  int c = threadIdx.x;
  float mu = chan[c]/(float)NN;
  float var = chan[HD+c]/(float)NN - mu*mu;
  float scale = bng[c]*rsqrtf(var + 1e-5f);
  bnp[c] = bnb[c] - mu*scale;     // shift
  bnp[HD+c] = scale;              // scale
}

// ---------- gate[n] = relu(BN(g[n])) . g2_w + g2_b ----------
__global__ void k_gate(const unsigned short* __restrict__ g, const float* __restrict__ bnp,
                       const float* __restrict__ g2w, const float* __restrict__ g2b,
                       float* __restrict__ gate){
  int lane = threadIdx.x & 63;
  int n = blockIdx.x*4 + (threadIdx.x>>6);
  if (n >= NN) return;
  float s = 0.f;
  #pragma unroll
  for (int k=0;k<4;k++){
    int c = lane + k*64;
    float v = bf2f(g[(size_t)n*HD + c])*bnp[HD+c] + bnp[c];
    v = fmaxf(v, 0.f);
    s += v * g2w[c];
  }
  #pragma unroll
  for (int o=32;o>0;o>>=1) s += __shfl_down(s, o);
  if (lane==0) gate[n] = s + g2b[0];
}

// ---------- per-graph offsets from SORTED batch ----------
__global__ void k_goffs(const int* __restrict__ batch, int* __restrict__ goffs){
  int n = blockIdx.x*256 + threadIdx.x;
  if (n >= NN) return;
  int b = batch[n];
  int prev = (n == 0) ? -1 : batch[n-1];
  for (int gg = prev+1; gg <= b; gg++) goffs[gg] = n;
  if (n == NN-1){ for (int gg = b+1; gg <= NBATCH; gg++) goffs[gg] = NN; }
}

// ---------- fused per-graph: softmax(gate) -> weighted pool of h2 -> out ----------
__global__ __launch_bounds__(256) void k_poolg(
    const unsigned short* __restrict__ h2, const float* __restrict__ gate,
    const int* __restrict__ goffs, const float* __restrict__ glw,
    const float* __restrict__ glb, float* __restrict__ out){
  __shared__ float red[256];
  int b = blockIdx.x, tid = threadIdx.x;
  int a = goffs[b], e = goffs[b+1];

  float m = -3.4e38f;
  for (int n = a + tid; n < e; n += 256) m = fmaxf(m, gate[n]);
  red[tid] = m; __syncthreads();
  for (int o = 128; o > 0; o >>= 1){ if (tid < o) red[tid] = fmaxf(red[tid], red[tid+o]); __syncthreads(); }
  m = red[0]; __syncthreads();

  float s = 0.f;
  for (int n = a + tid; n < e; n += 256) s += __expf(gate[n] - m);
  red[tid] = s; __syncthreads();
  for (int o = 128; o > 0; o >>= 1){ if (tid < o) red[tid] += red[tid+o]; __syncthreads(); }
  float denom = red[0] + 1e-16f; __syncthreads();

  float acc = 0.f;
  #pragma unroll 4
  for (int n = a; n < e; n++){
    float ev = __expf(gate[n] - m);
    acc += ev * bf2f(h2[(size_t)n*HD + tid]);
  }
  acc /= denom;

  red[tid] = acc * glw[tid]; __syncthreads();
  for (int o = 128; o > 0; o >>= 1){ if (tid < o) red[tid] += red[tid+o]; __syncthreads(); }
  if (tid == 0) out[b] = sigf(red[0] + glb[0]);
}

extern "C" void kernel_launch(void* const* d_in, const int* in_sizes, int n_in,
                              void* d_out, int out_size, void* d_ws, size_t ws_size,
                              hipStream_t stream) {
  const int* x     = (const int*)d_in[0];
  const int* ei    = (const int*)d_in[1];
  const int* et    = (const int*)d_in[2];
  const int* batch = (const int*)d_in[3];
  const float* emb0 = (const float*)d_in[4];
  const float* emb1 = (const float*)d_in[5];
  const float* emb2 = (const float*)d_in[6];
  const float* emb3 = (const float*)d_in[7];
  const float* emb4 = (const float*)d_in[8];
  const float* emb5 = (const float*)d_in[9];
  const float* W1    = (const float*)d_in[10];
  const float* root1 = (const float*)d_in[11];
  const float* b1    = (const float*)d_in[12];
  const float* W2    = (const float*)d_in[13];  // [R,H,O] flat == [1024,256]
  const float* root2 = (const float*)d_in[14];
  const float* b2    = (const float*)d_in[15];
  const float* g1w   = (const float*)d_in[16];
  const float* g1b   = (const float*)d_in[17];
  const float* bng   = (const float*)d_in[18];
  const float* bnb   = (const float*)d_in[19];
  const float* g2w   = (const float*)d_in[20];
  const float* g2b   = (const float*)d_in[21];
  const float* glw   = (const float*)d_in[22];
  const float* glb   = (const float*)d_in[23];
  float* out = (float*)d_out;

  // ---- workspace carve-up (256B aligned), total ≈ 133 MB ----
  char* w = (char*)d_ws;
  auto alloc = [&](size_t bytes)->char* {
    char* p = w; w += (bytes + 255) & ~(size_t)255; return p;
  };
  // slotA: A1 -> rootbuf -> g   (25.6 MB)
  char* slotA = alloc((size_t)NN*HD*2);
  unsigned short* A1      = (unsigned short*)slotA;
  unsigned short* rootbuf = (unsigned short*)slotA;
  unsigned short* g       = (unsigned short*)slotA;
  // slotH: h1 -> h2             (25.6 MB)
  unsigned short* h1 = (unsigned short*)alloc((size_t)NN*HD*2);
  unsigned short* h2 = h1;
  // slotZ: zbuf (both passes)   (51.2 MB)
  unsigned short* zbuf = (unsigned short*)alloc((size_t)NN*512*2);
  // pacc                        (25.6 MB)
  unsigned short* pacc = (unsigned short*)alloc((size_t)NN*HD*2);
  int*   cnt  = (int*)alloc((size_t)NSEG*sizeof(int));
  int*   cursor = cnt;   // scan3 reads cnt then writes cursor: alias-safe
  int*   offs = (int*)alloc((size_t)(NSEG+1)*sizeof(int));
  int*   bsum = (int*)alloc((size_t)SC_NB*sizeof(int));
  int*   boff = (int*)alloc((size_t)SC_NB*sizeof(int));
  int*   esrc = (int*)alloc((size_t)NE*sizeof(int));
  float* W1eff= (float*)alloc((size_t)200*HD*sizeof(float));
  float* R1eff= (float*)alloc((size_t)50*HD*sizeof(float));
  unsigned short* B1t  = (unsigned short*)alloc((size_t)256*256*2);
  unsigned short* Btz1 = (unsigned short*)alloc((size_t)768*256*2);  // [W2_0;W2_1;root2]^T
  unsigned short* Btz2 = (unsigned short*)alloc((size_t)512*256*2);  // [W2_2;W2_3]^T
  unsigned short* g1wt = (unsigned short*)alloc((size_t)256*256*2);
  float* gate = (float*)alloc((size_t)NN*sizeof(float));
  int*   goffs= (int*)alloc((size_t)(NBATCH+1)*sizeof(int));
  float* chan = (float*)alloc((size_t)2*HD*sizeof(float));
  float* bnp  = (float*)alloc((size_t)2*HD*sizeof(float));

  // ---- zero init ----
  hipMemsetAsync(cnt,  0, (size_t)NSEG*sizeof(int), stream);
  hipMemsetAsync(chan, 0, (size_t)2*HD*sizeof(float), stream);

  // ---- folded layer-1 weights, bf16 transposed weight assembly ----
  k_weff<<<NR*50, HD, 0, stream>>>(emb0,emb1,emb2,emb3,emb4,emb5, W1, 384*HD, W1eff);
  k_weff<<<50,    HD, 0, stream>>>(emb0,emb1,emb2,emb3,emb4,emb5, root1, 0, R1eff);
  k_b1t<<<256, 256, 0, stream>>>(W1eff, R1eff, B1t);
  k_tconv<<<256, 256, 0, stream>>>(W2,               Btz1,           256, 256);
  k_tconv<<<256, 256, 0, stream>>>(W2 + 256*256,     Btz1 + 256*256, 256, 256);
  k_tconv<<<256, 256, 0, stream>>>(root2,            Btz1 + 512*256, 256, 256);
  k_tconv<<<256, 256, 0, stream>>>(W2 + 2*256*256,   Btz2,           256, 256);
  k_tconv<<<256, 256, 0, stream>>>(W2 + 3*256*256,   Btz2 + 256*256, 256, 256);
  k_tconv<<<256, 256, 0, stream>>>(g1w,              g1wt,           256, 256);

  // ---- CSR build (counts -> scan -> bin) ----
  k_cnt<<<(NE+255)/256, 256, 0, stream>>>(ei, et, cnt);
  k_scan1<<<SC_NB, SC_T, 0, stream>>>(cnt, bsum);
  k_scan2<<<1, 256, 0, stream>>>(bsum, boff, offs);
  k_scan3<<<SC_NB, SC_T, 0, stream>>>(cnt, boff, offs, cursor);
  k_bin<<<(NE+255)/256, 256, 0, stream>>>(ei, et, cursor, esrc);

  // ---- A1 from CSR gather ----
  k_buildseg<<<NN, 256, 0, stream>>>(x, offs, esrc, A1);

  // ---- per-graph offsets (independent) ----
  k_goffs<<<(NN+255)/256, 256, 0, stream>>>(batch, goffs);

  // ---- layer 1 GEMM: h1 = sigmoid(A1 @ B1 + b1)   grid (2,391) ----
  dim3 g256(2, (NN+127)/128);
  k_mfma<true><<<g256, 256, 0, stream>>>(A1, 256, B1t, b1, h1, 256, 256, nullptr, 0, NN);

  // ---- z pass 1: [z_r0|z_r1|root] = h1 @ Btz1^T   grid (6,391); root -> slotA (A1 dead) ----
  dim3 g768(6, (NN+127)/128);
  k_mfma<false><<<g768, 256, 0, stream>>>(h1, 256, Btz1, nullptr, zbuf, 512, 512, rootbuf, 256, NN);
  k_comb1<<<(NN*64+255)/256, 256, 0, stream>>>(offs, esrc, zbuf, pacc);

  // ---- z pass 2: [z_r2|z_r3] = h1 @ Btz2^T        grid (4,391) ----
  dim3 g512(4, (NN+127)/128);
  k_mfma<false><<<g512, 256, 0, stream>>>(h1, 256, Btz2, nullptr, zbuf, 512, 512, nullptr, 0, NN);
  k_comb2<<<(NN*64+255)/256, 256, 0, stream>>>(offs, esrc, zbuf, pacc, rootbuf, b2, h2); // h2 over h1 (dead)

  // ---- gate linear: g = h2 @ g1w + g1b (bf16, over rootbuf: dead) ----
  k_mfma<false><<<g256, 256, 0, stream>>>(h2, 256, g1wt, g1b, g, 256, 256, nullptr, 0, NN);
  k_bnstats<<<(NN+127)/128, HD, 0, stream>>>(g, chan);
  k_bnfin<<<1, HD, 0, stream>>>(chan, bng, bnb, bnp);

  // ---- gate scalar + fused per-graph softmax/pool/output ----
  k_gate<<<(NN+3)/4, 256, 0, stream>>>(g, bnp, g2w, g2b, gate);
  k_poolg<<<NBATCH, 256, 0, stream>>>(h2, gate, goffs, glw, glb, out);
}